// Round 1
// 865.879 us; speedup vs baseline: 1.1977x; 1.1977x over previous
//
#include <hip/hip_runtime.h>
#include <hip/hip_bf16.h>

#define NA 150000
#define NT 200000
#define E_AT 1000000
#define E_TA 1000000
#define E_AA 500000

#define CHK 4096           // edges per k_bin block (smaller chunk -> 4x more blocks)
#define CAP 8192           // slot capacity per bin (max bin count ~3.8K)
#define P_AT 391           // ceil(NT/512)
#define P_TA 293           // ceil(NA/512)
#define P_AA 293
#define NBINS (P_AT + P_TA + P_AA)   // 977
#define CB_AT 245          // ceil(E_AT/CHK)
#define CB_TA 245
#define CB_AA 123

// ---------- dtype-flexible load: flag==1 -> fp32, flag==0 -> bf16 ----------
__device__ __forceinline__ float ldf(const void* p, long i, int f32) {
    if (f32) return ((const float*)p)[i];
    unsigned int u = ((const unsigned short*)p)[i];
    union { unsigned int ui; float f; } v; v.ui = u << 16;
    return v.f;
}
__device__ __forceinline__ float bf2f(unsigned short u) {
    union { unsigned int ui; float f; } v; v.ui = ((unsigned int)u) << 16;
    return v.f;
}
__device__ __forceinline__ float ftanh(float x) {
    x = fminf(fmaxf(x, -9.f), 9.f);
    float e = __expf(2.f * x);
    return (e - 1.f) / (e + 1.f);
}

// ---------- detect fp32 (1) vs bf16 (0) float inputs ----------
__global__ void k_detect(const void* __restrict__ x, int* __restrict__ flag) {
    __shared__ int cnt;
    if (threadIdx.x == 0) cnt = 0;
    __syncthreads();
    const unsigned short* u = (const unsigned short*)x;
    int wild = 0;
    for (int i = threadIdx.x; i < 4096; i += 256) {
        unsigned short v = u[i];
        int e = (v >> 7) & 0xFF;
        if (e > 133 || (e != 0 && e < 100)) wild++;
        else if (e == 0 && (v & 0x7F)) wild++;
    }
    atomicAdd(&cnt, wild);
    __syncthreads();
    if (threadIdx.x == 0) *flag = (cnt > 1024) ? 1 : 0;
}

// ========== fused projection + per-head attention dots ==========
// XMODE: 0 = global input (dtype-flagged), 1 = ws fp32, 2 = combine(o1,o2,attn)+relu
template<int K, bool ISADDR, int XMODE>
__global__ __launch_bounds__(256) void k_proj_fused(
        const void* __restrict__ X, const void* __restrict__ X2,
        const float* __restrict__ attn,
        const void* __restrict__ W, int wOff,
        const void* __restrict__ B, int bOff,
        float* __restrict__ H, int N,
        const void* __restrict__ attS, const void* __restrict__ attD, int lBase,
        float* __restrict__ a0p, float* __restrict__ a1p,
        float* __restrict__ a2p, float* __restrict__ a3p,
        const int* __restrict__ flagp) {
    constexpr int XS = K + 4;
    __shared__ float Ws[K * 32];
    __shared__ float Xs[64 * XS];
    const int f32 = *flagp;
    const int t = threadIdx.x;
    for (int i = t; i < K * 32; i += 256) Ws[i] = ldf(W, wOff + i, f32);
    const long n0 = (long)blockIdx.x * 64;
    constexpr int TOT4 = 64 * K / 4;
    if (XMODE == 2) {
        const float w0 = attn[0], w1 = attn[1];
        const float* Xa = (const float*)X;
        const float* Xb = (const float*)X2;
        for (int i = t; i < TOT4; i += 256) {
            int g = i * 4;
            int r = g / K, c = g & (K - 1);
            long gr = n0 + r; if (gr >= N) gr = N - 1;
            float4 va = *(const float4*)&Xa[gr * K + c];
            float4 vb = *(const float4*)&Xb[gr * K + c];
            float* dst = &Xs[r * XS + c];
            float v0 = w0 * va.x + w1 * vb.x;
            float v1 = w0 * va.y + w1 * vb.y;
            float v2 = w0 * va.z + w1 * vb.z;
            float v3 = w0 * va.w + w1 * vb.w;
            dst[0] = (v0 > 0.f) ? v0 : 0.f;
            dst[1] = (v1 > 0.f) ? v1 : 0.f;
            dst[2] = (v2 > 0.f) ? v2 : 0.f;
            dst[3] = (v3 > 0.f) ? v3 : 0.f;
        }
    } else if (XMODE == 1 || f32) {
        const float* Xf = (const float*)X;
        for (int i = t; i < TOT4; i += 256) {
            int g = i * 4;
            int r = g / K, c = g & (K - 1);
            long gr = n0 + r; if (gr >= N) gr = N - 1;
            float4 v = *(const float4*)&Xf[gr * K + c];
            float* dst = &Xs[r * XS + c];
            dst[0] = v.x; dst[1] = v.y; dst[2] = v.z; dst[3] = v.w;
        }
    } else {
        const unsigned short* Xh = (const unsigned short*)X;
        for (int i = t; i < TOT4; i += 256) {
            int g = i * 4;
            int r = g / K, c = g & (K - 1);
            long gr = n0 + r; if (gr >= N) gr = N - 1;
            ushort4 v = *(const ushort4*)&Xh[gr * K + c];
            float* dst = &Xs[r * XS + c];
            dst[0] = bf2f(v.x); dst[1] = bf2f(v.y); dst[2] = bf2f(v.z); dst[3] = bf2f(v.w);
        }
    }
    __syncthreads();
    const int nl = t >> 2, cg = t & 3;
    const long n = n0 + nl;
    float acc[8];
#pragma unroll
    for (int j = 0; j < 8; j++) acc[j] = ldf(B, bOff + cg * 8 + j, f32);
#pragma unroll
    for (int k = 0; k < K; k += 4) {
        float4 xv = *(const float4*)&Xs[nl * XS + k];
        const float x0 = xv.x, x1 = xv.y, x2 = xv.z, x3 = xv.w;
        const float* w0 = &Ws[(k + 0) * 32 + cg * 8];
        const float* w1 = &Ws[(k + 1) * 32 + cg * 8];
        const float* w2 = &Ws[(k + 2) * 32 + cg * 8];
        const float* w3 = &Ws[(k + 3) * 32 + cg * 8];
#pragma unroll
        for (int j = 0; j < 8; j++)
            acc[j] += x0 * w0[j] + x1 * w1[j] + x2 * w2[j] + x3 * w3[j];
    }
    if (n < N) {
        float* hp = &H[n * 32 + cg * 8];
        *(float4*)hp       = make_float4(acc[0], acc[1], acc[2], acc[3]);
        *(float4*)(hp + 4) = make_float4(acc[4], acc[5], acc[6], acc[7]);
        const int b = lBase + cg * 8;
        float d0 = 0.f, d1 = 0.f, d2 = 0.f, d3 = 0.f;
#pragma unroll
        for (int d = 0; d < 8; d++) {
            float x = acc[d];
            if (ISADDR) {
                d0 += x * ldf(attS, b + d, f32);
                d1 += x * ldf(attD, b + 32 + d, f32);
                d2 += x * ldf(attS, b + 64 + d, f32);
                d3 += x * ldf(attD, b + 64 + d, f32);
            } else {
                d0 += x * ldf(attD, b + d, f32);
                d1 += x * ldf(attS, b + 32 + d, f32);
            }
        }
        a0p[n * 4 + cg] = d0;
        a1p[n * 4 + cg] = d1;
        if (ISADDR) { a2p[n * 4 + cg] = d2; a3p[n * 4 + cg] = d3; }
    }
}

// ================= binned CSR build =================
// Phase A: bin edges by dst>>9 into fixed-capacity slots. pack = (ldst<<18)|src.
__global__ __launch_bounds__(256) void k_bin(
        const int* __restrict__ eat_s, const int* __restrict__ eat_d,
        const int* __restrict__ eta_s, const int* __restrict__ eta_d,
        const int* __restrict__ eaa_s, const int* __restrict__ eaa_d,
        int* __restrict__ gcnt,
        int* __restrict__ slot_at, int* __restrict__ slot_ta, int* __restrict__ slot_aa) {
    __shared__ int hist[P_AT];   // max bins per relation
    int b = blockIdx.x, t = threadIdx.x;
    const int *src, *dst; int E, P, seg; int* slot;
    if (b < CB_AT)              { src = eat_s; dst = eat_d; E = E_AT; P = P_AT; seg = 0;            slot = slot_at; }
    else if (b < CB_AT + CB_TA) { b -= CB_AT;  src = eta_s; dst = eta_d; E = E_TA; P = P_TA; seg = P_AT;        slot = slot_ta; }
    else                        { b -= CB_AT + CB_TA; src = eaa_s; dst = eaa_d; E = E_AA; P = P_AA; seg = P_AT + P_TA; slot = slot_aa; }
    long e0 = (long)b * CHK;
    for (int i = t; i < P; i += 256) hist[i] = 0;
    __syncthreads();
    for (int k = 0; k < CHK; k += 256) {
        long e = e0 + k + t;
        if (e < E) atomicAdd(&hist[dst[e] >> 9], 1);
    }
    __syncthreads();
    // reserve runs: hist[i] becomes this block's base cursor within bin i
    for (int i = t; i < P; i += 256) {
        int v = hist[i];
        hist[i] = atomicAdd(&gcnt[seg + i], v);
    }
    __syncthreads();
    for (int k = 0; k < CHK; k += 256) {
        long e = e0 + k + t;
        if (e < E) {
            int d = dst[e];
            int bin = d >> 9;
            int pos = atomicAdd(&hist[bin], 1);
            slot[bin * CAP + pos] = ((d & 511) << 18) | src[e];
        }
    }
}

// Phase A2: exclusive-scan bin counts per relation -> bin bases; write off[N].
__global__ void k_binscan(const int* __restrict__ gcnt, int* __restrict__ bbase,
                          int* __restrict__ off_at, int* __restrict__ off_ta,
                          int* __restrict__ off_aa) {
    __shared__ int sa[512], sb[512];
    int t = threadIdx.x;  // 512 threads
    const int segs[4] = {0, P_AT, P_AT + P_TA, NBINS};
    for (int r = 0; r < 3; r++) {
        int s0 = segs[r], P = segs[r + 1] - s0;
        sa[t] = (t < P) ? gcnt[s0 + t] : 0;
        __syncthreads();
        int* in = sa; int* out = sb;
        for (int o = 1; o < 512; o <<= 1) {
            out[t] = in[t] + (t >= o ? in[t - o] : 0);
            __syncthreads();
            int* tmp = in; in = out; out = tmp;
        }
        if (t < P) bbase[s0 + t] = (t ? in[t - 1] : 0);
        __syncthreads();
    }
    if (t == 0) { off_at[NT] = E_AT; off_ta[NA] = E_TA; off_aa[NA] = E_AA; }
}

// Phase B: per-bin LDS counting sort -> exact CSR + off. One block per bin;
// scattered csr writes stay inside a ~15 KB single-XCD window.
__global__ __launch_bounds__(256) void k_binsort(
        const int* __restrict__ gcnt, const int* __restrict__ bbase,
        const int* __restrict__ slot_at, const int* __restrict__ slot_ta,
        const int* __restrict__ slot_aa,
        int* __restrict__ off_at, int* __restrict__ off_ta, int* __restrict__ off_aa,
        int* __restrict__ csr_at, int* __restrict__ csr_ta, int* __restrict__ csr_aa) {
    __shared__ int sa[512], sb[512], cur[512];
    int b = blockIdx.x, t = threadIdx.x;
    const int* slot; int* off; int* csr; int N, bin, seg;
    if (b < P_AT)              { slot = slot_at; off = off_at; csr = csr_at; N = NT; bin = b;                seg = 0; }
    else if (b < P_AT + P_TA)  { slot = slot_ta; off = off_ta; csr = csr_ta; N = NA; bin = b - P_AT;         seg = P_AT; }
    else                       { slot = slot_aa; off = off_aa; csr = csr_aa; N = NA; bin = b - P_AT - P_TA;  seg = P_AT + P_TA; }
    const int cnt  = gcnt[seg + bin];
    const int base = bbase[seg + bin];
    const int* sp = &slot[bin * CAP];
    sa[t] = 0; sa[t + 256] = 0;
    __syncthreads();
    for (int i = t; i < cnt; i += 256) atomicAdd(&sa[sp[i] >> 18], 1);
    __syncthreads();
    int* in = sa; int* out = sb;
    for (int o = 1; o < 512; o <<= 1) {
        for (int i = t; i < 512; i += 256)
            out[i] = in[i] + (i >= o ? in[i - o] : 0);
        __syncthreads();
        int* tmp = in; in = out; out = tmp;
    }
    for (int i = t; i < 512; i += 256) {
        int excl = i ? in[i - 1] : 0;
        cur[i] = excl;
        int gd = bin * 512 + i;
        if (gd < N) off[gd] = base + excl;
    }
    __syncthreads();
    for (int i = t; i < cnt; i += 256) {
        int pk = sp[i];
        int pos = atomicAdd(&cur[pk >> 18], 1);
        csr[base + pos] = pk & 0x3FFFF;
    }
}

// ========== tri-relation gather: 32 lanes/dst ==========
// Lane j: edge-group g=j>>3 (4 edges in parallel), column-quad q=j&7
// (columns q*4..q*4+3, head hh=q>>1). Neighbor list fetched coalesced
// (32 indices in one load), broadcast via shfl; each lane does one 4B
// alpha load + one 16B float4 H load per edge -> 4 loads in flight per
// lane with the 8-edge unroll. Butterfly shfl_xor reduction per dst.
__global__ __launch_bounds__(256) void k_gather3(
        const int* __restrict__ off_at, const int* __restrict__ csr_at,
        const int* __restrict__ off_ta, const int* __restrict__ csr_ta,
        const int* __restrict__ off_aa, const int* __restrict__ csr_aa,
        const float* __restrict__ as0, const float* __restrict__ ad0,
        const float* __restrict__ as1, const float* __restrict__ ad1,
        const float* __restrict__ as2, const float* __restrict__ ad2,
        const float* __restrict__ h_a, const float* __restrict__ h_t,
        float* __restrict__ o_tx, float* __restrict__ o_a1, float* __restrict__ o_a2) {
    int tid = blockIdx.x * blockDim.x + threadIdx.x;
    int u = tid >> 5;
    int j = tid & 31;
    int g = j >> 3;          // edge sub-slot 0..3
    int q = j & 7;           // column quad 0..7
    int hh = q >> 1;         // head for columns q*4..q*4+3
    const int *off, *csr;
    const float *as_, *ad_, *Hs;
    float* O;
    int n;
    if (u < NT) {
        n = u; off = off_at; csr = csr_at; as_ = as0; ad_ = ad0; Hs = h_a; O = o_tx;
    } else if (u < NT + NA) {
        n = u - NT; off = off_ta; csr = csr_ta; as_ = as1; ad_ = ad1; Hs = h_t; O = o_a1;
    } else if (u < NT + 2 * NA) {
        n = u - NT - NA; off = off_aa; csr = csr_aa; as_ = as2; ad_ = ad2; Hs = h_a; O = o_a2;
    } else return;
    float adv = ad_[n * 4 + hh];
    int p0 = off[n], p1 = off[n + 1];
    float ax = 0.f, ay = 0.f, az = 0.f, aw = 0.f, se = 0.f;
    for (int base = p0; base < p1; base += 32) {
        int rem = p1 - base; if (rem > 32) rem = 32;
        int sv = (j < rem) ? csr[base + j] : 0;   // coalesced neighbor-list fetch
        for (int e4 = 0; e4 < rem; e4 += 8) {
            int eA = e4 + g, eB = e4 + 4 + g;
            int sA = __shfl(sv, eA, 32);
            int sB = __shfl(sv, eB, 32);
            float Aa = as_[sA * 4 + hh];
            float4 Ha = *(const float4*)&Hs[sA * 32 + q * 4];
            float Ab = as_[sB * 4 + hh];
            float4 Hb = *(const float4*)&Hs[sB * 32 + q * 4];
            float la = Aa + adv; la = fmaxf(la, 0.2f * la);
            float lb = Ab + adv; lb = fmaxf(lb, 0.2f * lb);
            float ea = (eA < rem) ? __expf(la) : 0.f;
            float eb = (eB < rem) ? __expf(lb) : 0.f;
            se += ea + eb;
            ax += ea * Ha.x + eb * Hb.x;
            ay += ea * Ha.y + eb * Hb.y;
            az += ea * Ha.z + eb * Hb.z;
            aw += ea * Ha.w + eb * Hb.w;
        }
    }
    // acc: sum the 4 edge-groups (lanes xor 8, 16 share q)
    ax += __shfl_xor(ax, 8, 32);  ay += __shfl_xor(ay, 8, 32);
    az += __shfl_xor(az, 8, 32);  aw += __shfl_xor(aw, 8, 32);
    ax += __shfl_xor(ax, 16, 32); ay += __shfl_xor(ay, 16, 32);
    az += __shfl_xor(az, 16, 32); aw += __shfl_xor(aw, 16, 32);
    // se: lanes (q pair) duplicate each exp 2x -> reduce 1,8,16 then halve
    se += __shfl_xor(se, 1, 32);
    se += __shfl_xor(se, 8, 32);
    se += __shfl_xor(se, 16, 32);
    float inv = 1.f / (0.5f * se + 1e-16f);
    if (j < 8) {
        float4 r;
        r.x = fmaxf(ax * inv, 0.f);
        r.y = fmaxf(ay * inv, 0.f);
        r.z = fmaxf(az * inv, 0.f);
        r.w = fmaxf(aw * inv, 0.f);
        *(float4*)&O[n * 32 + q * 4] = r;
    }
}

// ---------- fused dual semantic reduce ----------
__global__ void k_sem_reduce2(const float* __restrict__ O1, const float* __restrict__ O2, int N,
                              const void* __restrict__ kWp, int kwOff,
                              const void* __restrict__ kbp, int kbOff,
                              float* __restrict__ accum, const int* __restrict__ flagp) {
    int f32 = *flagp;
    __shared__ float w[1056];
    __shared__ float sacc[64];
    for (int i = threadIdx.x; i < 1024; i += blockDim.x) w[i] = ldf(kWp, kwOff + i, f32);
    if (threadIdx.x < 32) w[1024 + threadIdx.x] = ldf(kbp, kbOff + threadIdx.x, f32);
    if (threadIdx.x < 64) sacc[threadIdx.x] = 0.f;
    __syncthreads();
    int n = blockIdx.x * blockDim.x + threadIdx.x;
    const float* Os[2] = { O1, O2 };
#pragma unroll
    for (int r = 0; r < 2; r++) {
        float y[32];
        if (n < N) {
            float x[32];
#pragma unroll
            for (int k = 0; k < 32; k++) x[k] = Os[r][(long)n * 32 + k];
#pragma unroll
            for (int f = 0; f < 32; f++) {
                float acc = w[1024 + f];
#pragma unroll
                for (int k = 0; k < 32; k++) acc += x[k] * w[k * 32 + f];
                y[f] = ftanh(acc);
            }
        } else {
#pragma unroll
            for (int f = 0; f < 32; f++) y[f] = 0.f;
        }
#pragma unroll
        for (int f = 0; f < 32; f++) {
            float v = y[f];
            for (int o = 32; o > 0; o >>= 1) v += __shfl_xor(v, o, 64);
            if ((threadIdx.x & 63) == 0) atomicAdd(&sacc[r * 32 + f], v);
        }
    }
    __syncthreads();
    if (threadIdx.x < 64) atomicAdd(&accum[threadIdx.x], sacc[threadIdx.x]);
}

__global__ void k_sem_attn(const float* __restrict__ accum, float Ninv,
                           const void* __restrict__ q, int qOff,
                           float* __restrict__ attn, const int* __restrict__ flagp) {
    if (threadIdx.x == 0) {
        int f32 = *flagp;
        float s0 = 0.f, s1 = 0.f;
        for (int f = 0; f < 32; f++) {
            float qf = ldf(q, qOff + f, f32);
            s0 += accum[f] * Ninv * qf;
            s1 += accum[32 + f] * Ninv * qf;
        }
        float m = fmaxf(s0, s1);
        float e0 = __expf(s0 - m), e1 = __expf(s1 - m);
        float inv = 1.f / (e0 + e1);
        attn[0] = e0 * inv;
        attn[1] = e1 * inv;
    }
}

// ---------- fused combine + final linear (layer 3 only) ----------
__global__ void k_combine_final(const float* __restrict__ o1, const float* __restrict__ o2,
                                const float* __restrict__ attn,
                                const void* __restrict__ linW, const void* __restrict__ linb,
                                void* __restrict__ out, int N, const int* __restrict__ flagp) {
    int n = blockIdx.x * blockDim.x + threadIdx.x;
    if (n >= N) return;
    int f32 = *flagp;
    float w0 = attn[0], w1 = attn[1];
    float s0 = ldf(linb, 0, f32), s1 = ldf(linb, 1, f32);
    const float* p1 = &o1[(long)n * 32];
    const float* p2 = &o2[(long)n * 32];
#pragma unroll
    for (int f = 0; f < 32; f++) {
        float v = w0 * p1[f] + w1 * p2[f];
        v = (v > 0.f) ? v : 0.f;
        s0 += v * ldf(linW, f * 2, f32);
        s1 += v * ldf(linW, f * 2 + 1, f32);
    }
    if (f32) { ((float*)out)[n * 2] = s0; ((float*)out)[n * 2 + 1] = s1; }
    else {
        ((__hip_bfloat16*)out)[n * 2] = __float2bfloat16(s0);
        ((__hip_bfloat16*)out)[n * 2 + 1] = __float2bfloat16(s1);
    }
}

static inline int gblocks(long n) { return (int)((n + 255) / 256); }

extern "C" void kernel_launch(void* const* d_in, const int* in_sizes, int n_in,
                              void* d_out, int out_size, void* d_ws, size_t ws_size,
                              hipStream_t stream) {
    const void* x_addr = d_in[0];
    const void* x_tx   = d_in[1];
    const int* eat_s = (const int*)d_in[2];
    const int* eat_d = (const int*)d_in[3];
    const int* eta_s = (const int*)d_in[4];
    const int* eta_d = (const int*)d_in[5];
    const int* eaa_s = (const int*)d_in[6];
    const int* eaa_d = (const int*)d_in[7];
    const void* pW1  = d_in[8];
    const void* pb1  = d_in[9];
    const void* pW23 = d_in[10];
    const void* pb23 = d_in[11];
    const void* attS = d_in[12];
    const void* attD = d_in[13];
    const void* kW   = d_in[14];
    const void* kb   = d_in[15];
    const void* qv   = d_in[16];
    const void* linW = d_in[17];
    const void* linb = d_in[18];

    const size_t NA32 = (size_t)NA * 32, NT32 = (size_t)NT * 32;
    const size_t NA4 = (size_t)NA * 4, NT4 = (size_t)NT * 4;

    float* ws    = (float*)d_ws;
    float* h_a   = ws;
    float* h_t   = h_a + NA32;
    float* o_a1  = h_t + NT32;
    float* o_a2  = o_a1 + NA32;
    float* o_tx  = o_a2 + NA32;
    float* as0   = o_tx + NT32;
    float* ad1   = as0 + NA4;
    float* as2   = ad1 + NA4;
    float* ad2   = as2 + NA4;
    float* as1   = ad2 + NA4;
    float* ad0   = as1 + NT4;
    float* sem   = ad0 + NT4;            // 64 accum + 2 attn
    int*   flagp = (int*)(sem + 66);
    int*   off_at = flagp + 16;          // NT+1
    int*   off_ta = off_at + (NT + 1);   // NA+1
    int*   off_aa = off_ta + (NA + 1);   // NA+1
    int*   csr_at = off_aa + (NA + 1);   // E_AT
    int*   csr_ta = csr_at + E_AT;       // E_TA
    int*   csr_aa = csr_ta + E_TA;       // E_AA
    int*   gcnt   = csr_aa + E_AA;       // 1024
    int*   bbase  = gcnt + 1024;         // 1024
    int*   slot_at = bbase + 1024;       // P_AT*CAP
    int*   slot_ta = slot_at + P_AT * CAP;
    int*   slot_aa = slot_ta + P_TA * CAP;

    k_detect<<<1, 256, 0, stream>>>(x_addr, flagp);

    // ---- binned CSR build ----
    (void)hipMemsetAsync(gcnt, 0, 1024 * sizeof(int), stream);
    k_bin<<<CB_AT + CB_TA + CB_AA, 256, 0, stream>>>(
        eat_s, eat_d, eta_s, eta_d, eaa_s, eaa_d, gcnt, slot_at, slot_ta, slot_aa);
    k_binscan<<<1, 512, 0, stream>>>(gcnt, bbase, off_at, off_ta, off_aa);
    k_binsort<<<NBINS, 256, 0, stream>>>(gcnt, bbase, slot_at, slot_ta, slot_aa,
                                         off_at, off_ta, off_aa, csr_at, csr_ta, csr_aa);

    const int gA = (NA + 63) / 64, gT = (NT + 63) / 64;
    float* o_a1_prev = o_a1;
    float* o_a2_prev = o_a2;

    for (int l = 0; l < 3; l++) {
        if (l == 0) {
            k_proj_fused<64, true, 0><<<gA, 256, 0, stream>>>(
                x_addr, nullptr, nullptr, pW1, 0, pb1, 0, h_a, NA, attS, attD, 0,
                as0, ad1, as2, ad2, flagp);
            k_proj_fused<64, false, 0><<<gT, 256, 0, stream>>>(
                x_tx, nullptr, nullptr, pW1, 2048, pb1, 32, h_t, NT, attS, attD, 0,
                ad0, as1, nullptr, nullptr, flagp);
        } else {
            int wi = (l - 1) * 2;
            k_proj_fused<32, true, 2><<<gA, 256, 0, stream>>>(
                o_a1_prev, o_a2_prev, sem + 64, pW23, (wi + 0) * 1024, pb23, (wi + 0) * 32,
                h_a, NA, attS, attD, l * 96, as0, ad1, as2, ad2, flagp);
            k_proj_fused<32, false, 1><<<gT, 256, 0, stream>>>(
                o_tx, nullptr, nullptr, pW23, (wi + 1) * 1024, pb23, (wi + 1) * 32,
                h_t, NT, attS, attD, l * 96, ad0, as1, nullptr, nullptr, flagp);
        }
        k_gather3<<<gblocks((long)(NT + 2 * NA) * 32), 256, 0, stream>>>(
            off_at, csr_at, off_ta, csr_ta, off_aa, csr_aa,
            as0, ad0, as1, ad1, as2, ad2, h_a, h_t, o_tx, o_a1, o_a2);
        (void)hipMemsetAsync(sem, 0, 66 * sizeof(float), stream);
        k_sem_reduce2<<<gblocks(NA), 256, 0, stream>>>(o_a1, o_a2, NA, kW, l * 1024, kb, l * 32,
                                                       sem, flagp);
        k_sem_attn<<<1, 64, 0, stream>>>(sem, 1.0f / NA, qv, l * 32, sem + 64, flagp);
        if (l == 2) {
            k_combine_final<<<gblocks(NA), 256, 0, stream>>>(o_a1, o_a2, sem + 64,
                                                             linW, linb, d_out, NA, flagp);
        }
        o_a1_prev = o_a1;
        o_a2_prev = o_a2;
    }
}

// Round 2
// 845.381 us; speedup vs baseline: 1.2268x; 1.0242x over previous
//
#include <hip/hip_runtime.h>
#include <hip/hip_bf16.h>

#define NA 150000
#define NT 200000
#define E_AT 1000000
#define E_TA 1000000
#define E_AA 500000

#define CHK 4096           // edges per k_bin block
#define CAP 8192           // slot capacity per bin (max bin count ~3.8K)
#define P_AT 391           // ceil(NT/512)
#define P_TA 293           // ceil(NA/512)
#define P_AA 293
#define NBINS (P_AT + P_TA + P_AA)   // 977
#define CB_AT 245          // ceil(E_AT/CHK)
#define CB_TA 245
#define CB_AA 123

// gather grid partition: 32 dsts per 256-thread block (8 lanes per dst)
#define GB_AT 6250         // ceil(NT/32)
#define GB_TA 4688         // ceil(NA/32)
#define GB_AA 4688

// ---------- dtype-flexible load: flag==1 -> fp32, flag==0 -> bf16 ----------
__device__ __forceinline__ float ldf(const void* p, long i, int f32) {
    if (f32) return ((const float*)p)[i];
    unsigned int u = ((const unsigned short*)p)[i];
    union { unsigned int ui; float f; } v; v.ui = u << 16;
    return v.f;
}
__device__ __forceinline__ float bf2f(unsigned short u) {
    union { unsigned int ui; float f; } v; v.ui = ((unsigned int)u) << 16;
    return v.f;
}
__device__ __forceinline__ float ftanh(float x) {
    x = fminf(fmaxf(x, -9.f), 9.f);
    float e = __expf(2.f * x);
    return (e - 1.f) / (e + 1.f);
}

// ---------- detect fp32 (1) vs bf16 (0) float inputs ----------
__global__ void k_detect(const void* __restrict__ x, int* __restrict__ flag) {
    __shared__ int cnt;
    if (threadIdx.x == 0) cnt = 0;
    __syncthreads();
    const unsigned short* u = (const unsigned short*)x;
    int wild = 0;
    for (int i = threadIdx.x; i < 4096; i += 256) {
        unsigned short v = u[i];
        int e = (v >> 7) & 0xFF;
        if (e > 133 || (e != 0 && e < 100)) wild++;
        else if (e == 0 && (v & 0x7F)) wild++;
    }
    atomicAdd(&cnt, wild);
    __syncthreads();
    if (threadIdx.x == 0) *flag = (cnt > 1024) ? 1 : 0;
}

// ========== fused projection + per-head attention dots ==========
// XMODE: 0 = global input (dtype-flagged), 1 = ws fp32, 2 = combine(o1,o2,attn)+relu
template<int K, bool ISADDR, int XMODE>
__global__ __launch_bounds__(256) void k_proj_fused(
        const void* __restrict__ X, const void* __restrict__ X2,
        const float* __restrict__ attn,
        const void* __restrict__ W, int wOff,
        const void* __restrict__ B, int bOff,
        float* __restrict__ H, int N,
        const void* __restrict__ attS, const void* __restrict__ attD, int lBase,
        float* __restrict__ a0p, float* __restrict__ a1p,
        float* __restrict__ a2p, float* __restrict__ a3p,
        const int* __restrict__ flagp) {
    constexpr int XS = K + 4;
    __shared__ float Ws[K * 32];
    __shared__ float Xs[64 * XS];
    const int f32 = *flagp;
    const int t = threadIdx.x;
    for (int i = t; i < K * 32; i += 256) Ws[i] = ldf(W, wOff + i, f32);
    const long n0 = (long)blockIdx.x * 64;
    constexpr int TOT4 = 64 * K / 4;
    if (XMODE == 2) {
        const float w0 = attn[0], w1 = attn[1];
        const float* Xa = (const float*)X;
        const float* Xb = (const float*)X2;
        for (int i = t; i < TOT4; i += 256) {
            int g = i * 4;
            int r = g / K, c = g & (K - 1);
            long gr = n0 + r; if (gr >= N) gr = N - 1;
            float4 va = *(const float4*)&Xa[gr * K + c];
            float4 vb = *(const float4*)&Xb[gr * K + c];
            float* dst = &Xs[r * XS + c];
            float v0 = w0 * va.x + w1 * vb.x;
            float v1 = w0 * va.y + w1 * vb.y;
            float v2 = w0 * va.z + w1 * vb.z;
            float v3 = w0 * va.w + w1 * vb.w;
            dst[0] = (v0 > 0.f) ? v0 : 0.f;
            dst[1] = (v1 > 0.f) ? v1 : 0.f;
            dst[2] = (v2 > 0.f) ? v2 : 0.f;
            dst[3] = (v3 > 0.f) ? v3 : 0.f;
        }
    } else if (XMODE == 1 || f32) {
        const float* Xf = (const float*)X;
        for (int i = t; i < TOT4; i += 256) {
            int g = i * 4;
            int r = g / K, c = g & (K - 1);
            long gr = n0 + r; if (gr >= N) gr = N - 1;
            float4 v = *(const float4*)&Xf[gr * K + c];
            float* dst = &Xs[r * XS + c];
            dst[0] = v.x; dst[1] = v.y; dst[2] = v.z; dst[3] = v.w;
        }
    } else {
        const unsigned short* Xh = (const unsigned short*)X;
        for (int i = t; i < TOT4; i += 256) {
            int g = i * 4;
            int r = g / K, c = g & (K - 1);
            long gr = n0 + r; if (gr >= N) gr = N - 1;
            ushort4 v = *(const ushort4*)&Xh[gr * K + c];
            float* dst = &Xs[r * XS + c];
            dst[0] = bf2f(v.x); dst[1] = bf2f(v.y); dst[2] = bf2f(v.z); dst[3] = bf2f(v.w);
        }
    }
    __syncthreads();
    const int nl = t >> 2, cg = t & 3;
    const long n = n0 + nl;
    float acc[8];
#pragma unroll
    for (int j = 0; j < 8; j++) acc[j] = ldf(B, bOff + cg * 8 + j, f32);
#pragma unroll
    for (int k = 0; k < K; k += 4) {
        float4 xv = *(const float4*)&Xs[nl * XS + k];
        const float x0 = xv.x, x1 = xv.y, x2 = xv.z, x3 = xv.w;
        const float* w0 = &Ws[(k + 0) * 32 + cg * 8];
        const float* w1 = &Ws[(k + 1) * 32 + cg * 8];
        const float* w2 = &Ws[(k + 2) * 32 + cg * 8];
        const float* w3 = &Ws[(k + 3) * 32 + cg * 8];
#pragma unroll
        for (int j = 0; j < 8; j++)
            acc[j] += x0 * w0[j] + x1 * w1[j] + x2 * w2[j] + x3 * w3[j];
    }
    if (n < N) {
        float* hp = &H[n * 32 + cg * 8];
        *(float4*)hp       = make_float4(acc[0], acc[1], acc[2], acc[3]);
        *(float4*)(hp + 4) = make_float4(acc[4], acc[5], acc[6], acc[7]);
        const int b = lBase + cg * 8;
        float d0 = 0.f, d1 = 0.f, d2 = 0.f, d3 = 0.f;
#pragma unroll
        for (int d = 0; d < 8; d++) {
            float x = acc[d];
            if (ISADDR) {
                d0 += x * ldf(attS, b + d, f32);
                d1 += x * ldf(attD, b + 32 + d, f32);
                d2 += x * ldf(attS, b + 64 + d, f32);
                d3 += x * ldf(attD, b + 64 + d, f32);
            } else {
                d0 += x * ldf(attD, b + d, f32);
                d1 += x * ldf(attS, b + 32 + d, f32);
            }
        }
        a0p[n * 4 + cg] = d0;
        a1p[n * 4 + cg] = d1;
        if (ISADDR) { a2p[n * 4 + cg] = d2; a3p[n * 4 + cg] = d3; }
    }
}

// ================= binned CSR build =================
// Phase A: bin edges by dst>>9 into fixed-capacity slots. pack = (ldst<<18)|src.
__global__ __launch_bounds__(256) void k_bin(
        const int* __restrict__ eat_s, const int* __restrict__ eat_d,
        const int* __restrict__ eta_s, const int* __restrict__ eta_d,
        const int* __restrict__ eaa_s, const int* __restrict__ eaa_d,
        int* __restrict__ gcnt,
        int* __restrict__ slot_at, int* __restrict__ slot_ta, int* __restrict__ slot_aa) {
    __shared__ int hist[P_AT];   // max bins per relation
    int b = blockIdx.x, t = threadIdx.x;
    const int *src, *dst; int E, P, seg; int* slot;
    if (b < CB_AT)              { src = eat_s; dst = eat_d; E = E_AT; P = P_AT; seg = 0;            slot = slot_at; }
    else if (b < CB_AT + CB_TA) { b -= CB_AT;  src = eta_s; dst = eta_d; E = E_TA; P = P_TA; seg = P_AT;        slot = slot_ta; }
    else                        { b -= CB_AT + CB_TA; src = eaa_s; dst = eaa_d; E = E_AA; P = P_AA; seg = P_AT + P_TA; slot = slot_aa; }
    long e0 = (long)b * CHK;
    for (int i = t; i < P; i += 256) hist[i] = 0;
    __syncthreads();
    for (int k = 0; k < CHK; k += 256) {
        long e = e0 + k + t;
        if (e < E) atomicAdd(&hist[dst[e] >> 9], 1);
    }
    __syncthreads();
    // reserve runs: hist[i] becomes this block's base cursor within bin i
    for (int i = t; i < P; i += 256) {
        int v = hist[i];
        hist[i] = atomicAdd(&gcnt[seg + i], v);
    }
    __syncthreads();
    for (int k = 0; k < CHK; k += 256) {
        long e = e0 + k + t;
        if (e < E) {
            int d = dst[e];
            int bin = d >> 9;
            int pos = atomicAdd(&hist[bin], 1);
            slot[bin * CAP + pos] = ((d & 511) << 18) | src[e];
        }
    }
}

// Phase A2: exclusive-scan bin counts per relation -> bin bases; write off[N].
__global__ void k_binscan(const int* __restrict__ gcnt, int* __restrict__ bbase,
                          int* __restrict__ off_at, int* __restrict__ off_ta,
                          int* __restrict__ off_aa) {
    __shared__ int sa[512], sb[512];
    int t = threadIdx.x;  // 512 threads
    const int segs[4] = {0, P_AT, P_AT + P_TA, NBINS};
    for (int r = 0; r < 3; r++) {
        int s0 = segs[r], P = segs[r + 1] - s0;
        sa[t] = (t < P) ? gcnt[s0 + t] : 0;
        __syncthreads();
        int* in = sa; int* out = sb;
        for (int o = 1; o < 512; o <<= 1) {
            out[t] = in[t] + (t >= o ? in[t - o] : 0);
            __syncthreads();
            int* tmp = in; in = out; out = tmp;
        }
        if (t < P) bbase[s0 + t] = (t ? in[t - 1] : 0);
        __syncthreads();
    }
    if (t == 0) { off_at[NT] = E_AT; off_ta[NA] = E_TA; off_aa[NA] = E_AA; }
}

// Phase B: per-bin LDS counting sort -> exact CSR + off. One block per bin;
// scattered csr writes stay inside a ~15 KB single-XCD window.
__global__ __launch_bounds__(256) void k_binsort(
        const int* __restrict__ gcnt, const int* __restrict__ bbase,
        const int* __restrict__ slot_at, const int* __restrict__ slot_ta,
        const int* __restrict__ slot_aa,
        int* __restrict__ off_at, int* __restrict__ off_ta, int* __restrict__ off_aa,
        int* __restrict__ csr_at, int* __restrict__ csr_ta, int* __restrict__ csr_aa) {
    __shared__ int sa[512], sb[512], cur[512];
    int b = blockIdx.x, t = threadIdx.x;
    const int* slot; int* off; int* csr; int N, bin, seg;
    if (b < P_AT)              { slot = slot_at; off = off_at; csr = csr_at; N = NT; bin = b;                seg = 0; }
    else if (b < P_AT + P_TA)  { slot = slot_ta; off = off_ta; csr = csr_ta; N = NA; bin = b - P_AT;         seg = P_AT; }
    else                       { slot = slot_aa; off = off_aa; csr = csr_aa; N = NA; bin = b - P_AT - P_TA;  seg = P_AT + P_TA; }
    const int cnt  = gcnt[seg + bin];
    const int base = bbase[seg + bin];
    const int* sp = &slot[bin * CAP];
    sa[t] = 0; sa[t + 256] = 0;
    __syncthreads();
    for (int i = t; i < cnt; i += 256) atomicAdd(&sa[sp[i] >> 18], 1);
    __syncthreads();
    int* in = sa; int* out = sb;
    for (int o = 1; o < 512; o <<= 1) {
        for (int i = t; i < 512; i += 256)
            out[i] = in[i] + (i >= o ? in[i - o] : 0);
        __syncthreads();
        int* tmp = in; in = out; out = tmp;
    }
    for (int i = t; i < 512; i += 256) {
        int excl = i ? in[i - 1] : 0;
        cur[i] = excl;
        int gd = bin * 512 + i;
        if (gd < N) off[gd] = base + excl;
    }
    __syncthreads();
    for (int i = t; i < cnt; i += 256) {
        int pk = sp[i];
        int pos = atomicAdd(&cur[pk >> 18], 1);
        csr[base + pos] = pk & 0x3FFFF;
    }
}

// ========== tri-relation gather: 8 lanes per dst, relation uniform per block ==========
// Lane q in [0,8) owns columns q*4..q*4+3 (head hh=q>>1) for its dst ENTIRELY:
// per-lane private acc (float4) and softmax denominator se -> zero cross-lane
// reduction. Relation picked from blockIdx ranges -> all base pointers stay in
// SGPRs (saddr + 32-bit voffset addressing, 1 VALU per load). Edge loop 4x
// unrolled: 12 independent loads in flight per lane body; csr loads broadcast-
// coalesce across the 8 lanes, H reads are 8 consecutive float4 = 128 B.
__global__ __launch_bounds__(256) void k_gather3(
        const int* __restrict__ off_at, const int* __restrict__ csr_at,
        const int* __restrict__ off_ta, const int* __restrict__ csr_ta,
        const int* __restrict__ off_aa, const int* __restrict__ csr_aa,
        const float* __restrict__ as0, const float* __restrict__ ad0,
        const float* __restrict__ as1, const float* __restrict__ ad1,
        const float* __restrict__ as2, const float* __restrict__ ad2,
        const float* __restrict__ h_a, const float* __restrict__ h_t,
        float* __restrict__ o_tx, float* __restrict__ o_a1, float* __restrict__ o_a2) {
    int b = blockIdx.x;
    const int *off, *csr;
    const float *as_, *ad_, *Hs;
    float* O;
    int N;
    if (b < GB_AT) {
        off = off_at; csr = csr_at; as_ = as0; ad_ = ad0; Hs = h_a; O = o_tx; N = NT;
    } else if (b < GB_AT + GB_TA) {
        b -= GB_AT;
        off = off_ta; csr = csr_ta; as_ = as1; ad_ = ad1; Hs = h_t; O = o_a1; N = NA;
    } else {
        b -= GB_AT + GB_TA;
        off = off_aa; csr = csr_aa; as_ = as2; ad_ = ad2; Hs = h_a; O = o_a2; N = NA;
    }
    const int t = threadIdx.x;
    const int q = t & 7;          // column quad 0..7
    const int hh = q >> 1;        // head
    const int n = b * 32 + (t >> 3);
    if (n >= N) return;
    const float adv = ad_[n * 4 + hh];
    const int p0 = off[n], p1 = off[n + 1];
    float ax = 0.f, ay = 0.f, az = 0.f, aw = 0.f, se = 0.f;
    int p = p0;
    for (; p + 4 <= p1; p += 4) {
        int s0 = csr[p], s1 = csr[p + 1], s2 = csr[p + 2], s3 = csr[p + 3];
        float A0 = as_[s0 * 4 + hh], A1 = as_[s1 * 4 + hh];
        float A2 = as_[s2 * 4 + hh], A3 = as_[s3 * 4 + hh];
        float4 H0 = *(const float4*)&Hs[s0 * 32 + q * 4];
        float4 H1 = *(const float4*)&Hs[s1 * 32 + q * 4];
        float4 H2 = *(const float4*)&Hs[s2 * 32 + q * 4];
        float4 H3 = *(const float4*)&Hs[s3 * 32 + q * 4];
        float l0 = A0 + adv; l0 = fmaxf(l0, 0.2f * l0); float e0 = __expf(l0);
        float l1 = A1 + adv; l1 = fmaxf(l1, 0.2f * l1); float e1 = __expf(l1);
        float l2 = A2 + adv; l2 = fmaxf(l2, 0.2f * l2); float e2 = __expf(l2);
        float l3 = A3 + adv; l3 = fmaxf(l3, 0.2f * l3); float e3 = __expf(l3);
        se += e0 + e1 + e2 + e3;
        ax += e0 * H0.x + e1 * H1.x + e2 * H2.x + e3 * H3.x;
        ay += e0 * H0.y + e1 * H1.y + e2 * H2.y + e3 * H3.y;
        az += e0 * H0.z + e1 * H1.z + e2 * H2.z + e3 * H3.z;
        aw += e0 * H0.w + e1 * H1.w + e2 * H2.w + e3 * H3.w;
    }
    for (; p < p1; p++) {
        int s = csr[p];
        float A = as_[s * 4 + hh];
        float4 H = *(const float4*)&Hs[s * 32 + q * 4];
        float l = A + adv; l = fmaxf(l, 0.2f * l);
        float e = __expf(l);
        se += e;
        ax += e * H.x; ay += e * H.y; az += e * H.z; aw += e * H.w;
    }
    const float inv = 1.f / (se + 1e-16f);
    float4 r;
    r.x = fmaxf(ax * inv, 0.f);
    r.y = fmaxf(ay * inv, 0.f);
    r.z = fmaxf(az * inv, 0.f);
    r.w = fmaxf(aw * inv, 0.f);
    *(float4*)&O[n * 32 + q * 4] = r;
}

// ---------- fused dual semantic reduce ----------
__global__ void k_sem_reduce2(const float* __restrict__ O1, const float* __restrict__ O2, int N,
                              const void* __restrict__ kWp, int kwOff,
                              const void* __restrict__ kbp, int kbOff,
                              float* __restrict__ accum, const int* __restrict__ flagp) {
    int f32 = *flagp;
    __shared__ float w[1056];
    __shared__ float sacc[64];
    for (int i = threadIdx.x; i < 1024; i += blockDim.x) w[i] = ldf(kWp, kwOff + i, f32);
    if (threadIdx.x < 32) w[1024 + threadIdx.x] = ldf(kbp, kbOff + threadIdx.x, f32);
    if (threadIdx.x < 64) sacc[threadIdx.x] = 0.f;
    __syncthreads();
    int n = blockIdx.x * blockDim.x + threadIdx.x;
    const float* Os[2] = { O1, O2 };
#pragma unroll
    for (int r = 0; r < 2; r++) {
        float y[32];
        if (n < N) {
            float x[32];
#pragma unroll
            for (int k = 0; k < 32; k++) x[k] = Os[r][(long)n * 32 + k];
#pragma unroll
            for (int f = 0; f < 32; f++) {
                float acc = w[1024 + f];
#pragma unroll
                for (int k = 0; k < 32; k++) acc += x[k] * w[k * 32 + f];
                y[f] = ftanh(acc);
            }
        } else {
#pragma unroll
            for (int f = 0; f < 32; f++) y[f] = 0.f;
        }
#pragma unroll
        for (int f = 0; f < 32; f++) {
            float v = y[f];
            for (int o = 32; o > 0; o >>= 1) v += __shfl_xor(v, o, 64);
            if ((threadIdx.x & 63) == 0) atomicAdd(&sacc[r * 32 + f], v);
        }
    }
    __syncthreads();
    if (threadIdx.x < 64) atomicAdd(&accum[threadIdx.x], sacc[threadIdx.x]);
}

__global__ void k_sem_attn(const float* __restrict__ accum, float Ninv,
                           const void* __restrict__ q, int qOff,
                           float* __restrict__ attn, const int* __restrict__ flagp) {
    if (threadIdx.x == 0) {
        int f32 = *flagp;
        float s0 = 0.f, s1 = 0.f;
        for (int f = 0; f < 32; f++) {
            float qf = ldf(q, qOff + f, f32);
            s0 += accum[f] * Ninv * qf;
            s1 += accum[32 + f] * Ninv * qf;
        }
        float m = fmaxf(s0, s1);
        float e0 = __expf(s0 - m), e1 = __expf(s1 - m);
        float inv = 1.f / (e0 + e1);
        attn[0] = e0 * inv;
        attn[1] = e1 * inv;
    }
}

// ---------- fused combine + final linear (layer 3 only) ----------
__global__ void k_combine_final(const float* __restrict__ o1, const float* __restrict__ o2,
                                const float* __restrict__ attn,
                                const void* __restrict__ linW, const void* __restrict__ linb,
                                void* __restrict__ out, int N, const int* __restrict__ flagp) {
    int n = blockIdx.x * blockDim.x + threadIdx.x;
    if (n >= N) return;
    int f32 = *flagp;
    float w0 = attn[0], w1 = attn[1];
    float s0 = ldf(linb, 0, f32), s1 = ldf(linb, 1, f32);
    const float* p1 = &o1[(long)n * 32];
    const float* p2 = &o2[(long)n * 32];
#pragma unroll
    for (int f = 0; f < 32; f++) {
        float v = w0 * p1[f] + w1 * p2[f];
        v = (v > 0.f) ? v : 0.f;
        s0 += v * ldf(linW, f * 2, f32);
        s1 += v * ldf(linW, f * 2 + 1, f32);
    }
    if (f32) { ((float*)out)[n * 2] = s0; ((float*)out)[n * 2 + 1] = s1; }
    else {
        ((__hip_bfloat16*)out)[n * 2] = __float2bfloat16(s0);
        ((__hip_bfloat16*)out)[n * 2 + 1] = __float2bfloat16(s1);
    }
}

static inline int gblocks(long n) { return (int)((n + 255) / 256); }

extern "C" void kernel_launch(void* const* d_in, const int* in_sizes, int n_in,
                              void* d_out, int out_size, void* d_ws, size_t ws_size,
                              hipStream_t stream) {
    const void* x_addr = d_in[0];
    const void* x_tx   = d_in[1];
    const int* eat_s = (const int*)d_in[2];
    const int* eat_d = (const int*)d_in[3];
    const int* eta_s = (const int*)d_in[4];
    const int* eta_d = (const int*)d_in[5];
    const int* eaa_s = (const int*)d_in[6];
    const int* eaa_d = (const int*)d_in[7];
    const void* pW1  = d_in[8];
    const void* pb1  = d_in[9];
    const void* pW23 = d_in[10];
    const void* pb23 = d_in[11];
    const void* attS = d_in[12];
    const void* attD = d_in[13];
    const void* kW   = d_in[14];
    const void* kb   = d_in[15];
    const void* qv   = d_in[16];
    const void* linW = d_in[17];
    const void* linb = d_in[18];

    const size_t NA32 = (size_t)NA * 32, NT32 = (size_t)NT * 32;
    const size_t NA4 = (size_t)NA * 4, NT4 = (size_t)NT * 4;

    float* ws    = (float*)d_ws;
    float* h_a   = ws;
    float* h_t   = h_a + NA32;
    float* o_a1  = h_t + NT32;
    float* o_a2  = o_a1 + NA32;
    float* o_tx  = o_a2 + NA32;
    float* as0   = o_tx + NT32;
    float* ad1   = as0 + NA4;
    float* as2   = ad1 + NA4;
    float* ad2   = as2 + NA4;
    float* as1   = ad2 + NA4;
    float* ad0   = as1 + NT4;
    float* sem   = ad0 + NT4;            // 64 accum + 2 attn
    int*   flagp = (int*)(sem + 66);
    int*   off_at = flagp + 16;          // NT+1
    int*   off_ta = off_at + (NT + 1);   // NA+1
    int*   off_aa = off_ta + (NA + 1);   // NA+1
    int*   csr_at = off_aa + (NA + 1);   // E_AT
    int*   csr_ta = csr_at + E_AT;       // E_TA
    int*   csr_aa = csr_ta + E_TA;       // E_AA
    int*   gcnt   = csr_aa + E_AA;       // 1024
    int*   bbase  = gcnt + 1024;         // 1024
    int*   slot_at = bbase + 1024;       // P_AT*CAP
    int*   slot_ta = slot_at + P_AT * CAP;
    int*   slot_aa = slot_ta + P_TA * CAP;

    k_detect<<<1, 256, 0, stream>>>(x_addr, flagp);

    // ---- binned CSR build ----
    (void)hipMemsetAsync(gcnt, 0, 1024 * sizeof(int), stream);
    k_bin<<<CB_AT + CB_TA + CB_AA, 256, 0, stream>>>(
        eat_s, eat_d, eta_s, eta_d, eaa_s, eaa_d, gcnt, slot_at, slot_ta, slot_aa);
    k_binscan<<<1, 512, 0, stream>>>(gcnt, bbase, off_at, off_ta, off_aa);
    k_binsort<<<NBINS, 256, 0, stream>>>(gcnt, bbase, slot_at, slot_ta, slot_aa,
                                         off_at, off_ta, off_aa, csr_at, csr_ta, csr_aa);

    const int gA = (NA + 63) / 64, gT = (NT + 63) / 64;
    float* o_a1_prev = o_a1;
    float* o_a2_prev = o_a2;

    for (int l = 0; l < 3; l++) {
        if (l == 0) {
            k_proj_fused<64, true, 0><<<gA, 256, 0, stream>>>(
                x_addr, nullptr, nullptr, pW1, 0, pb1, 0, h_a, NA, attS, attD, 0,
                as0, ad1, as2, ad2, flagp);
            k_proj_fused<64, false, 0><<<gT, 256, 0, stream>>>(
                x_tx, nullptr, nullptr, pW1, 2048, pb1, 32, h_t, NT, attS, attD, 0,
                ad0, as1, nullptr, nullptr, flagp);
        } else {
            int wi = (l - 1) * 2;
            k_proj_fused<32, true, 2><<<gA, 256, 0, stream>>>(
                o_a1_prev, o_a2_prev, sem + 64, pW23, (wi + 0) * 1024, pb23, (wi + 0) * 32,
                h_a, NA, attS, attD, l * 96, as0, ad1, as2, ad2, flagp);
            k_proj_fused<32, false, 1><<<gT, 256, 0, stream>>>(
                o_tx, nullptr, nullptr, pW23, (wi + 1) * 1024, pb23, (wi + 1) * 32,
                h_t, NT, attS, attD, l * 96, ad0, as1, nullptr, nullptr, flagp);
        }
        k_gather3<<<GB_AT + GB_TA + GB_AA, 256, 0, stream>>>(
            off_at, csr_at, off_ta, csr_ta, off_aa, csr_aa,
            as0, ad0, as1, ad1, as2, ad2, h_a, h_t, o_tx, o_a1, o_a2);
        (void)hipMemsetAsync(sem, 0, 66 * sizeof(float), stream);
        k_sem_reduce2<<<gblocks(NA), 256, 0, stream>>>(o_a1, o_a2, NA, kW, l * 1024, kb, l * 32,
                                                       sem, flagp);
        k_sem_attn<<<1, 64, 0, stream>>>(sem, 1.0f / NA, qv, l * 32, sem + 64, flagp);
        if (l == 2) {
            k_combine_final<<<gblocks(NA), 256, 0, stream>>>(o_a1, o_a2, sem + 64,
                                                             linW, linb, d_out, NA, flagp);
        }
        o_a1_prev = o_a1;
        o_a2_prev = o_a2;
    }
}

// Round 3
// 764.692 us; speedup vs baseline: 1.3562x; 1.1055x over previous
//
#include <hip/hip_runtime.h>
#include <hip/hip_bf16.h>
#include <hip/hip_fp16.h>

#define NA 150000
#define NT 200000
#define E_AT 1000000
#define E_TA 1000000
#define E_AA 500000

#define CHK 4096           // edges per k_bin block
#define CAP 8192           // slot capacity per bin (max bin count ~3.8K)
#define P_AT 391           // ceil(NT/512)
#define P_TA 293           // ceil(NA/512)
#define P_AA 293
#define NBINS (P_AT + P_TA + P_AA)   // 977
#define CB_AT 245          // ceil(E_AT/CHK)
#define CB_TA 245
#define CB_AA 123

// gather grid partition: 32 dsts per 256-thread block (8 lanes per dst)
#define GB_AT 6250         // ceil(NT/32)
#define GB_TA 4688         // ceil(NA/32)
#define GB_AA 4688

// ---------- dtype-flexible load: flag==1 -> fp32, flag==0 -> bf16 ----------
__device__ __forceinline__ float ldf(const void* p, long i, int f32) {
    if (f32) return ((const float*)p)[i];
    unsigned int u = ((const unsigned short*)p)[i];
    union { unsigned int ui; float f; } v; v.ui = u << 16;
    return v.f;
}
__device__ __forceinline__ float bf2f(unsigned short u) {
    union { unsigned int ui; float f; } v; v.ui = ((unsigned int)u) << 16;
    return v.f;
}
__device__ __forceinline__ float h2f(unsigned short u) {
    return __half2float(__ushort_as_half(u));
}
__device__ __forceinline__ unsigned short f2h(float x) {
    return __half_as_ushort(__float2half(x));
}
__device__ __forceinline__ float ftanh(float x) {
    x = fminf(fmaxf(x, -9.f), 9.f);
    float e = __expf(2.f * x);
    return (e - 1.f) / (e + 1.f);
}

// ---------- detect fp32 (1) vs bf16 (0) float inputs ----------
__global__ void k_detect(const void* __restrict__ x, int* __restrict__ flag) {
    __shared__ int cnt;
    if (threadIdx.x == 0) cnt = 0;
    __syncthreads();
    const unsigned short* u = (const unsigned short*)x;
    int wild = 0;
    for (int i = threadIdx.x; i < 4096; i += 256) {
        unsigned short v = u[i];
        int e = (v >> 7) & 0xFF;
        if (e > 133 || (e != 0 && e < 100)) wild++;
        else if (e == 0 && (v & 0x7F)) wild++;
    }
    atomicAdd(&cnt, wild);
    __syncthreads();
    if (threadIdx.x == 0) *flag = (cnt > 1024) ? 1 : 0;
}

// ========== fused projection + dst-alpha dots; H stored fp16 ==========
// XMODE: 0 = global input (dtype-flagged), 1 = ws fp32, 2 = combine(o1,o2,attn)+relu
// aP/aQ get the DST-side attention dots (attD); source-side dots are
// recomputed in k_gather3 from the fp16 H row (saves a random fetch there).
// zsem (if non-null): block 0 zeroes the 64-float semantic accumulator,
// replacing a separate hipMemsetAsync dispatch.
template<int K, bool ISADDR, int XMODE>
__global__ __launch_bounds__(256) void k_proj_fused(
        const void* __restrict__ X, const void* __restrict__ X2,
        const float* __restrict__ attn,
        const void* __restrict__ W, int wOff,
        const void* __restrict__ B, int bOff,
        unsigned short* __restrict__ Hh, int N,
        const void* __restrict__ attD, int lBase,
        float* __restrict__ aP, float* __restrict__ aQ,
        const int* __restrict__ flagp, float* __restrict__ zsem) {
    constexpr int XS = K + 4;
    __shared__ float Ws[K * 32];
    __shared__ float Xs[64 * XS];
    const int f32 = *flagp;
    const int t = threadIdx.x;
    if (zsem && blockIdx.x == 0 && t < 64) zsem[t] = 0.f;
    for (int i = t; i < K * 32; i += 256) Ws[i] = ldf(W, wOff + i, f32);
    const long n0 = (long)blockIdx.x * 64;
    constexpr int TOT4 = 64 * K / 4;
    if (XMODE == 2) {
        const float w0 = attn[0], w1 = attn[1];
        const float* Xa = (const float*)X;
        const float* Xb = (const float*)X2;
        for (int i = t; i < TOT4; i += 256) {
            int g = i * 4;
            int r = g / K, c = g & (K - 1);
            long gr = n0 + r; if (gr >= N) gr = N - 1;
            float4 va = *(const float4*)&Xa[gr * K + c];
            float4 vb = *(const float4*)&Xb[gr * K + c];
            float* dst = &Xs[r * XS + c];
            float v0 = w0 * va.x + w1 * vb.x;
            float v1 = w0 * va.y + w1 * vb.y;
            float v2 = w0 * va.z + w1 * vb.z;
            float v3 = w0 * va.w + w1 * vb.w;
            dst[0] = (v0 > 0.f) ? v0 : 0.f;
            dst[1] = (v1 > 0.f) ? v1 : 0.f;
            dst[2] = (v2 > 0.f) ? v2 : 0.f;
            dst[3] = (v3 > 0.f) ? v3 : 0.f;
        }
    } else if (XMODE == 1 || f32) {
        const float* Xf = (const float*)X;
        for (int i = t; i < TOT4; i += 256) {
            int g = i * 4;
            int r = g / K, c = g & (K - 1);
            long gr = n0 + r; if (gr >= N) gr = N - 1;
            float4 v = *(const float4*)&Xf[gr * K + c];
            float* dst = &Xs[r * XS + c];
            dst[0] = v.x; dst[1] = v.y; dst[2] = v.z; dst[3] = v.w;
        }
    } else {
        const unsigned short* Xh = (const unsigned short*)X;
        for (int i = t; i < TOT4; i += 256) {
            int g = i * 4;
            int r = g / K, c = g & (K - 1);
            long gr = n0 + r; if (gr >= N) gr = N - 1;
            ushort4 v = *(const ushort4*)&Xh[gr * K + c];
            float* dst = &Xs[r * XS + c];
            dst[0] = bf2f(v.x); dst[1] = bf2f(v.y); dst[2] = bf2f(v.z); dst[3] = bf2f(v.w);
        }
    }
    __syncthreads();
    const int nl = t >> 2, cg = t & 3;
    const long n = n0 + nl;
    float acc[8];
#pragma unroll
    for (int j = 0; j < 8; j++) acc[j] = ldf(B, bOff + cg * 8 + j, f32);
#pragma unroll
    for (int k = 0; k < K; k += 4) {
        float4 xv = *(const float4*)&Xs[nl * XS + k];
        const float x0 = xv.x, x1 = xv.y, x2 = xv.z, x3 = xv.w;
        const float* w0 = &Ws[(k + 0) * 32 + cg * 8];
        const float* w1 = &Ws[(k + 1) * 32 + cg * 8];
        const float* w2 = &Ws[(k + 2) * 32 + cg * 8];
        const float* w3 = &Ws[(k + 3) * 32 + cg * 8];
#pragma unroll
        for (int j = 0; j < 8; j++)
            acc[j] += x0 * w0[j] + x1 * w1[j] + x2 * w2[j] + x3 * w3[j];
    }
    if (n < N) {
        // fp16 H row: 32 halves = 64 B = exactly one cacheline per node
        unsigned int u01 = (unsigned)f2h(acc[0]) | ((unsigned)f2h(acc[1]) << 16);
        unsigned int u23 = (unsigned)f2h(acc[2]) | ((unsigned)f2h(acc[3]) << 16);
        unsigned int u45 = (unsigned)f2h(acc[4]) | ((unsigned)f2h(acc[5]) << 16);
        unsigned int u67 = (unsigned)f2h(acc[6]) | ((unsigned)f2h(acc[7]) << 16);
        *(uint4*)&Hh[n * 32 + cg * 8] = make_uint4(u01, u23, u45, u67);
        const int b = lBase + cg * 8;
        float dP = 0.f, dQ = 0.f;
#pragma unroll
        for (int d = 0; d < 8; d++) {
            float x = acc[d];
            if (ISADDR) {
                dP += x * ldf(attD, b + 32 + d, f32);   // TA dst (edge type 1)
                dQ += x * ldf(attD, b + 64 + d, f32);   // AA dst (edge type 2)
            } else {
                dP += x * ldf(attD, b + d, f32);        // AT dst (edge type 0)
            }
        }
        aP[n * 4 + cg] = dP;
        if (ISADDR) aQ[n * 4 + cg] = dQ;
    }
}

// ================= binned CSR build =================
// Phase A: bin edges by dst>>9 into fixed-capacity slots. pack = (ldst<<18)|src.
__global__ __launch_bounds__(256) void k_bin(
        const int* __restrict__ eat_s, const int* __restrict__ eat_d,
        const int* __restrict__ eta_s, const int* __restrict__ eta_d,
        const int* __restrict__ eaa_s, const int* __restrict__ eaa_d,
        int* __restrict__ gcnt,
        int* __restrict__ slot_at, int* __restrict__ slot_ta, int* __restrict__ slot_aa) {
    __shared__ int hist[P_AT];   // max bins per relation
    int b = blockIdx.x, t = threadIdx.x;
    const int *src, *dst; int E, P, seg; int* slot;
    if (b < CB_AT)              { src = eat_s; dst = eat_d; E = E_AT; P = P_AT; seg = 0;            slot = slot_at; }
    else if (b < CB_AT + CB_TA) { b -= CB_AT;  src = eta_s; dst = eta_d; E = E_TA; P = P_TA; seg = P_AT;        slot = slot_ta; }
    else                        { b -= CB_AT + CB_TA; src = eaa_s; dst = eaa_d; E = E_AA; P = P_AA; seg = P_AT + P_TA; slot = slot_aa; }
    long e0 = (long)b * CHK;
    for (int i = t; i < P; i += 256) hist[i] = 0;
    __syncthreads();
    for (int k = 0; k < CHK; k += 256) {
        long e = e0 + k + t;
        if (e < E) atomicAdd(&hist[dst[e] >> 9], 1);
    }
    __syncthreads();
    // reserve runs: hist[i] becomes this block's base cursor within bin i
    for (int i = t; i < P; i += 256) {
        int v = hist[i];
        hist[i] = atomicAdd(&gcnt[seg + i], v);
    }
    __syncthreads();
    for (int k = 0; k < CHK; k += 256) {
        long e = e0 + k + t;
        if (e < E) {
            int d = dst[e];
            int bin = d >> 9;
            int pos = atomicAdd(&hist[bin], 1);
            slot[bin * CAP + pos] = ((d & 511) << 18) | src[e];
        }
    }
}

// Phase A2: exclusive-scan bin counts per relation -> bin bases; write off[N].
__global__ void k_binscan(const int* __restrict__ gcnt, int* __restrict__ bbase,
                          int* __restrict__ off_at, int* __restrict__ off_ta,
                          int* __restrict__ off_aa) {
    __shared__ int sa[512], sb[512];
    int t = threadIdx.x;  // 512 threads
    const int segs[4] = {0, P_AT, P_AT + P_TA, NBINS};
    for (int r = 0; r < 3; r++) {
        int s0 = segs[r], P = segs[r + 1] - s0;
        sa[t] = (t < P) ? gcnt[s0 + t] : 0;
        __syncthreads();
        int* in = sa; int* out = sb;
        for (int o = 1; o < 512; o <<= 1) {
            out[t] = in[t] + (t >= o ? in[t - o] : 0);
            __syncthreads();
            int* tmp = in; in = out; out = tmp;
        }
        if (t < P) bbase[s0 + t] = (t ? in[t - 1] : 0);
        __syncthreads();
    }
    if (t == 0) { off_at[NT] = E_AT; off_ta[NA] = E_TA; off_aa[NA] = E_AA; }
}

// Phase B: per-bin LDS counting sort -> exact CSR + off.
__global__ __launch_bounds__(256) void k_binsort(
        const int* __restrict__ gcnt, const int* __restrict__ bbase,
        const int* __restrict__ slot_at, const int* __restrict__ slot_ta,
        const int* __restrict__ slot_aa,
        int* __restrict__ off_at, int* __restrict__ off_ta, int* __restrict__ off_aa,
        int* __restrict__ csr_at, int* __restrict__ csr_ta, int* __restrict__ csr_aa) {
    __shared__ int sa[512], sb[512], cur[512];
    int b = blockIdx.x, t = threadIdx.x;
    const int* slot; int* off; int* csr; int N, bin, seg;
    if (b < P_AT)              { slot = slot_at; off = off_at; csr = csr_at; N = NT; bin = b;                seg = 0; }
    else if (b < P_AT + P_TA)  { slot = slot_ta; off = off_ta; csr = csr_ta; N = NA; bin = b - P_AT;         seg = P_AT; }
    else                       { slot = slot_aa; off = off_aa; csr = csr_aa; N = NA; bin = b - P_AT - P_TA;  seg = P_AT + P_TA; }
    const int cnt  = gcnt[seg + bin];
    const int base = bbase[seg + bin];
    const int* sp = &slot[bin * CAP];
    sa[t] = 0; sa[t + 256] = 0;
    __syncthreads();
    for (int i = t; i < cnt; i += 256) atomicAdd(&sa[sp[i] >> 18], 1);
    __syncthreads();
    int* in = sa; int* out = sb;
    for (int o = 1; o < 512; o <<= 1) {
        for (int i = t; i < 512; i += 256)
            out[i] = in[i] + (i >= o ? in[i - o] : 0);
        __syncthreads();
        int* tmp = in; in = out; out = tmp;
    }
    for (int i = t; i < 512; i += 256) {
        int excl = i ? in[i - 1] : 0;
        cur[i] = excl;
        int gd = bin * 512 + i;
        if (gd < N) off[gd] = base + excl;
    }
    __syncthreads();
    for (int i = t; i < cnt; i += 256) {
        int pk = sp[i];
        int pos = atomicAdd(&cur[pk >> 18], 1);
        csr[base + pos] = pk & 0x3FFFF;
    }
}

// ========== tri-relation gather: 8 lanes/dst, fp16 H, in-kernel src alpha ==========
// Per edge the 8-lane group fetches exactly ONE 64 B cacheline (the fp16 H row).
// Source alpha is recomputed from that row: lane q dots its 4 elements with
// att_src[head] (float4, loaded once) and a shfl_xor(·,1) completes the 8-dim
// per-head dot. Dst alpha (per dst, not per edge) is precomputed fp32.
__global__ __launch_bounds__(256) void k_gather3(
        const int* __restrict__ off_at, const int* __restrict__ csr_at,
        const int* __restrict__ off_ta, const int* __restrict__ csr_ta,
        const int* __restrict__ off_aa, const int* __restrict__ csr_aa,
        const float* __restrict__ ad0, const float* __restrict__ ad1,
        const float* __restrict__ ad2,
        const unsigned short* __restrict__ h_a, const unsigned short* __restrict__ h_t,
        float* __restrict__ o_tx, float* __restrict__ o_a1, float* __restrict__ o_a2,
        const void* __restrict__ attS, int lBase, const int* __restrict__ flagp) {
    int b = blockIdx.x;
    const int *off, *csr;
    const float *ad_;
    const unsigned short* Hs;
    float* O;
    int N, attOff;
    if (b < GB_AT) {
        off = off_at; csr = csr_at; ad_ = ad0; Hs = h_a; O = o_tx; N = NT;
        attOff = lBase;            // edge type 0 (A->T)
    } else if (b < GB_AT + GB_TA) {
        b -= GB_AT;
        off = off_ta; csr = csr_ta; ad_ = ad1; Hs = h_t; O = o_a1; N = NA;
        attOff = lBase + 32;       // edge type 1 (T->A)
    } else {
        b -= GB_AT + GB_TA;
        off = off_aa; csr = csr_aa; ad_ = ad2; Hs = h_a; O = o_a2; N = NA;
        attOff = lBase + 64;       // edge type 2 (A->A)
    }
    const int t = threadIdx.x;
    const int q = t & 7;          // column quad 0..7
    const int hh = q >> 1;        // head
    const int n = b * 32 + (t >> 3);
    if (n >= N) return;
    const int f32 = *flagp;
    const float aq0 = ldf(attS, attOff + q * 4 + 0, f32);
    const float aq1 = ldf(attS, attOff + q * 4 + 1, f32);
    const float aq2 = ldf(attS, attOff + q * 4 + 2, f32);
    const float aq3 = ldf(attS, attOff + q * 4 + 3, f32);
    const float adv = ad_[n * 4 + hh];
    const int p0 = off[n], p1 = off[n + 1];
    float ax = 0.f, ay = 0.f, az = 0.f, aw = 0.f, se = 0.f;
    int p = p0;
    for (; p + 4 <= p1; p += 4) {
        int s0 = csr[p], s1 = csr[p + 1], s2 = csr[p + 2], s3 = csr[p + 3];
        ushort4 v0 = *(const ushort4*)&Hs[s0 * 32 + q * 4];
        ushort4 v1 = *(const ushort4*)&Hs[s1 * 32 + q * 4];
        ushort4 v2 = *(const ushort4*)&Hs[s2 * 32 + q * 4];
        ushort4 v3 = *(const ushort4*)&Hs[s3 * 32 + q * 4];
        float h00 = h2f(v0.x), h01 = h2f(v0.y), h02 = h2f(v0.z), h03 = h2f(v0.w);
        float h10 = h2f(v1.x), h11 = h2f(v1.y), h12 = h2f(v1.z), h13 = h2f(v1.w);
        float h20 = h2f(v2.x), h21 = h2f(v2.y), h22 = h2f(v2.z), h23 = h2f(v2.w);
        float h30 = h2f(v3.x), h31 = h2f(v3.y), h32 = h2f(v3.z), h33 = h2f(v3.w);
        float pt0 = h00 * aq0 + h01 * aq1 + h02 * aq2 + h03 * aq3;
        float pt1 = h10 * aq0 + h11 * aq1 + h12 * aq2 + h13 * aq3;
        float pt2 = h20 * aq0 + h21 * aq1 + h22 * aq2 + h23 * aq3;
        float pt3 = h30 * aq0 + h31 * aq1 + h32 * aq2 + h33 * aq3;
        float al0 = pt0 + __shfl_xor(pt0, 1);
        float al1 = pt1 + __shfl_xor(pt1, 1);
        float al2 = pt2 + __shfl_xor(pt2, 1);
        float al3 = pt3 + __shfl_xor(pt3, 1);
        float l0 = al0 + adv; l0 = fmaxf(l0, 0.2f * l0); float e0 = __expf(l0);
        float l1 = al1 + adv; l1 = fmaxf(l1, 0.2f * l1); float e1 = __expf(l1);
        float l2 = al2 + adv; l2 = fmaxf(l2, 0.2f * l2); float e2 = __expf(l2);
        float l3 = al3 + adv; l3 = fmaxf(l3, 0.2f * l3); float e3 = __expf(l3);
        se += e0 + e1 + e2 + e3;
        ax += e0 * h00 + e1 * h10 + e2 * h20 + e3 * h30;
        ay += e0 * h01 + e1 * h11 + e2 * h21 + e3 * h31;
        az += e0 * h02 + e1 * h12 + e2 * h22 + e3 * h32;
        aw += e0 * h03 + e1 * h13 + e2 * h23 + e3 * h33;
    }
    for (; p < p1; p++) {
        int s = csr[p];
        ushort4 v = *(const ushort4*)&Hs[s * 32 + q * 4];
        float h0 = h2f(v.x), h1 = h2f(v.y), h2 = h2f(v.z), h3 = h2f(v.w);
        float pt = h0 * aq0 + h1 * aq1 + h2 * aq2 + h3 * aq3;
        float al = pt + __shfl_xor(pt, 1);
        float l = al + adv; l = fmaxf(l, 0.2f * l);
        float e = __expf(l);
        se += e;
        ax += e * h0; ay += e * h1; az += e * h2; aw += e * h3;
    }
    const float inv = 1.f / (se + 1e-16f);
    float4 r;
    r.x = fmaxf(ax * inv, 0.f);
    r.y = fmaxf(ay * inv, 0.f);
    r.z = fmaxf(az * inv, 0.f);
    r.w = fmaxf(aw * inv, 0.f);
    *(float4*)&O[n * 32 + q * 4] = r;
}

// ---------- fused dual semantic reduce ----------
__global__ void k_sem_reduce2(const float* __restrict__ O1, const float* __restrict__ O2, int N,
                              const void* __restrict__ kWp, int kwOff,
                              const void* __restrict__ kbp, int kbOff,
                              float* __restrict__ accum, const int* __restrict__ flagp) {
    int f32 = *flagp;
    __shared__ float w[1056];
    __shared__ float sacc[64];
    for (int i = threadIdx.x; i < 1024; i += blockDim.x) w[i] = ldf(kWp, kwOff + i, f32);
    if (threadIdx.x < 32) w[1024 + threadIdx.x] = ldf(kbp, kbOff + threadIdx.x, f32);
    if (threadIdx.x < 64) sacc[threadIdx.x] = 0.f;
    __syncthreads();
    int n = blockIdx.x * blockDim.x + threadIdx.x;
    const float* Os[2] = { O1, O2 };
#pragma unroll
    for (int r = 0; r < 2; r++) {
        float y[32];
        if (n < N) {
            float x[32];
#pragma unroll
            for (int k = 0; k < 32; k++) x[k] = Os[r][(long)n * 32 + k];
#pragma unroll
            for (int f = 0; f < 32; f++) {
                float acc = w[1024 + f];
#pragma unroll
                for (int k = 0; k < 32; k++) acc += x[k] * w[k * 32 + f];
                y[f] = ftanh(acc);
            }
        } else {
#pragma unroll
            for (int f = 0; f < 32; f++) y[f] = 0.f;
        }
#pragma unroll
        for (int f = 0; f < 32; f++) {
            float v = y[f];
            for (int o = 32; o > 0; o >>= 1) v += __shfl_xor(v, o, 64);
            if ((threadIdx.x & 63) == 0) atomicAdd(&sacc[r * 32 + f], v);
        }
    }
    __syncthreads();
    if (threadIdx.x < 64) atomicAdd(&accum[threadIdx.x], sacc[threadIdx.x]);
}

__global__ void k_sem_attn(const float* __restrict__ accum, float Ninv,
                           const void* __restrict__ q, int qOff,
                           float* __restrict__ attn, const int* __restrict__ flagp) {
    if (threadIdx.x == 0) {
        int f32 = *flagp;
        float s0 = 0.f, s1 = 0.f;
        for (int f = 0; f < 32; f++) {
            float qf = ldf(q, qOff + f, f32);
            s0 += accum[f] * Ninv * qf;
            s1 += accum[32 + f] * Ninv * qf;
        }
        float m = fmaxf(s0, s1);
        float e0 = __expf(s0 - m), e1 = __expf(s1 - m);
        float inv = 1.f / (e0 + e1);
        attn[0] = e0 * inv;
        attn[1] = e1 * inv;
    }
}

// ---------- fused combine + final linear (layer 3 only) ----------
__global__ void k_combine_final(const float* __restrict__ o1, const float* __restrict__ o2,
                                const float* __restrict__ attn,
                                const void* __restrict__ linW, const void* __restrict__ linb,
                                void* __restrict__ out, int N, const int* __restrict__ flagp) {
    int n = blockIdx.x * blockDim.x + threadIdx.x;
    if (n >= N) return;
    int f32 = *flagp;
    float w0 = attn[0], w1 = attn[1];
    float s0 = ldf(linb, 0, f32), s1 = ldf(linb, 1, f32);
    const float* p1 = &o1[(long)n * 32];
    const float* p2 = &o2[(long)n * 32];
#pragma unroll
    for (int f = 0; f < 32; f++) {
        float v = w0 * p1[f] + w1 * p2[f];
        v = (v > 0.f) ? v : 0.f;
        s0 += v * ldf(linW, f * 2, f32);
        s1 += v * ldf(linW, f * 2 + 1, f32);
    }
    if (f32) { ((float*)out)[n * 2] = s0; ((float*)out)[n * 2 + 1] = s1; }
    else {
        ((__hip_bfloat16*)out)[n * 2] = __float2bfloat16(s0);
        ((__hip_bfloat16*)out)[n * 2 + 1] = __float2bfloat16(s1);
    }
}

static inline int gblocks(long n) { return (int)((n + 255) / 256); }

extern "C" void kernel_launch(void* const* d_in, const int* in_sizes, int n_in,
                              void* d_out, int out_size, void* d_ws, size_t ws_size,
                              hipStream_t stream) {
    const void* x_addr = d_in[0];
    const void* x_tx   = d_in[1];
    const int* eat_s = (const int*)d_in[2];
    const int* eat_d = (const int*)d_in[3];
    const int* eta_s = (const int*)d_in[4];
    const int* eta_d = (const int*)d_in[5];
    const int* eaa_s = (const int*)d_in[6];
    const int* eaa_d = (const int*)d_in[7];
    const void* pW1  = d_in[8];
    const void* pb1  = d_in[9];
    const void* pW23 = d_in[10];
    const void* pb23 = d_in[11];
    const void* attS = d_in[12];
    const void* attD = d_in[13];
    const void* kW   = d_in[14];
    const void* kb   = d_in[15];
    const void* qv   = d_in[16];
    const void* linW = d_in[17];
    const void* linb = d_in[18];

    const size_t NA32 = (size_t)NA * 32, NT32 = (size_t)NT * 32;
    const size_t NA4 = (size_t)NA * 4, NT4 = (size_t)NT * 4;

    float* ws    = (float*)d_ws;
    float* h_aF  = ws;                   // fp16 rows (uses half the slot)
    float* h_tF  = h_aF + NA32;
    float* o_a1  = h_tF + NT32;
    float* o_a2  = o_a1 + NA32;
    float* o_tx  = o_a2 + NA32;
    float* ad1   = o_tx + NT32;          // TA dst alphas (addr)
    float* ad2   = ad1 + NA4;            // AA dst alphas (addr)
    float* ad0   = ad2 + NA4;            // AT dst alphas (tx)
    float* sem   = ad0 + NT4;            // 64 accum + 2 attn
    int*   flagp = (int*)(sem + 66);
    int*   off_at = flagp + 16;          // NT+1
    int*   off_ta = off_at + (NT + 1);   // NA+1
    int*   off_aa = off_ta + (NA + 1);   // NA+1
    int*   csr_at = off_aa + (NA + 1);   // E_AT
    int*   csr_ta = csr_at + E_AT;       // E_TA
    int*   csr_aa = csr_ta + E_TA;       // E_AA
    int*   gcnt   = csr_aa + E_AA;       // 1024
    int*   bbase  = gcnt + 1024;         // 1024
    int*   slot_at = bbase + 1024;       // P_AT*CAP
    int*   slot_ta = slot_at + P_AT * CAP;
    int*   slot_aa = slot_ta + P_TA * CAP;

    unsigned short* h_a = (unsigned short*)h_aF;
    unsigned short* h_t = (unsigned short*)h_tF;

    k_detect<<<1, 256, 0, stream>>>(x_addr, flagp);

    // ---- binned CSR build ----
    (void)hipMemsetAsync(gcnt, 0, 1024 * sizeof(int), stream);
    k_bin<<<CB_AT + CB_TA + CB_AA, 256, 0, stream>>>(
        eat_s, eat_d, eta_s, eta_d, eaa_s, eaa_d, gcnt, slot_at, slot_ta, slot_aa);
    k_binscan<<<1, 512, 0, stream>>>(gcnt, bbase, off_at, off_ta, off_aa);
    k_binsort<<<NBINS, 256, 0, stream>>>(gcnt, bbase, slot_at, slot_ta, slot_aa,
                                         off_at, off_ta, off_aa, csr_at, csr_ta, csr_aa);

    const int gA = (NA + 63) / 64, gT = (NT + 63) / 64;
    float* o_a1_prev = o_a1;
    float* o_a2_prev = o_a2;

    for (int l = 0; l < 3; l++) {
        if (l == 0) {
            k_proj_fused<64, true, 0><<<gA, 256, 0, stream>>>(
                x_addr, nullptr, nullptr, pW1, 0, pb1, 0, h_a, NA, attD, 0,
                ad1, ad2, flagp, sem);
            k_proj_fused<64, false, 0><<<gT, 256, 0, stream>>>(
                x_tx, nullptr, nullptr, pW1, 2048, pb1, 32, h_t, NT, attD, 0,
                ad0, nullptr, flagp, nullptr);
        } else {
            int wi = (l - 1) * 2;
            k_proj_fused<32, true, 2><<<gA, 256, 0, stream>>>(
                o_a1_prev, o_a2_prev, sem + 64, pW23, (wi + 0) * 1024, pb23, (wi + 0) * 32,
                h_a, NA, attD, l * 96, ad1, ad2, flagp, sem);
            k_proj_fused<32, false, 1><<<gT, 256, 0, stream>>>(
                o_tx, nullptr, nullptr, pW23, (wi + 1) * 1024, pb23, (wi + 1) * 32,
                h_t, NT, attD, l * 96, ad0, nullptr, flagp, nullptr);
        }
        k_gather3<<<GB_AT + GB_TA + GB_AA, 256, 0, stream>>>(
            off_at, csr_at, off_ta, csr_ta, off_aa, csr_aa,
            ad0, ad1, ad2, h_a, h_t, o_tx, o_a1, o_a2, attS, l * 96, flagp);
        k_sem_reduce2<<<gblocks(NA), 256, 0, stream>>>(o_a1, o_a2, NA, kW, l * 1024, kb, l * 32,
                                                       sem, flagp);
        k_sem_attn<<<1, 64, 0, stream>>>(sem, 1.0f / NA, qv, l * 32, sem + 64, flagp);
        if (l == 2) {
            k_combine_final<<<gblocks(NA), 256, 0, stream>>>(o_a1, o_a2, sem + 64,
                                                             linW, linb, d_out, NA, flagp);
        }
        o_a1_prev = o_a1;
        o_a2_prev = o_a2;
    }
}

// Round 4
// 743.274 us; speedup vs baseline: 1.3953x; 1.0288x over previous
//
#include <hip/hip_runtime.h>
#include <hip/hip_bf16.h>
#include <hip/hip_fp16.h>

#define NA 150000
#define NT 200000
#define E_AT 1000000
#define E_TA 1000000
#define E_AA 500000

#define CHK 2048           // edges per k_bin block (more blocks -> fill the machine)
#define CAP 8192           // slot capacity per bin (max bin count ~3.8K)
#define P_AT 391           // ceil(NT/512)
#define P_TA 293           // ceil(NA/512)
#define P_AA 293
#define NBINS (P_AT + P_TA + P_AA)   // 977
#define CB_AT 489          // ceil(E_AT/CHK)
#define CB_TA 489
#define CB_AA 245

// gather grid partition: 32 dsts per 256-thread block (8 lanes per dst)
#define GB_AT 6250         // ceil(NT/32)
#define GB_TA 4688         // ceil(NA/32)
#define GB_AA 4688

// merged proj grid partition: 64 nodes per block
#define GPA 2344           // ceil(NA/64)
#define GPT 3125           // NT/64
#define NB_SEM 586         // ceil(NA/256) blocks per relation for sem reduce

// ---------- dtype-flexible load: flag==1 -> fp32, flag==0 -> bf16 ----------
__device__ __forceinline__ float ldf(const void* p, long i, int f32) {
    if (f32) return ((const float*)p)[i];
    unsigned int u = ((const unsigned short*)p)[i];
    union { unsigned int ui; float f; } v; v.ui = u << 16;
    return v.f;
}
__device__ __forceinline__ float bf2f(unsigned short u) {
    union { unsigned int ui; float f; } v; v.ui = ((unsigned int)u) << 16;
    return v.f;
}
__device__ __forceinline__ float h2f(unsigned short u) {
    return __half2float(__ushort_as_half(u));
}
__device__ __forceinline__ unsigned short f2h(float x) {
    return __half_as_ushort(__float2half(x));
}
__device__ __forceinline__ float ftanh(float x) {
    x = fminf(fmaxf(x, -9.f), 9.f);
    float e = __expf(2.f * x);
    return (e - 1.f) / (e + 1.f);
}

// ---------- detect fp32 (1) vs bf16 (0) float inputs ----------
__global__ void k_detect(const void* __restrict__ x, int* __restrict__ flag) {
    __shared__ int cnt;
    if (threadIdx.x == 0) cnt = 0;
    __syncthreads();
    const unsigned short* u = (const unsigned short*)x;
    int wild = 0;
    for (int i = threadIdx.x; i < 4096; i += 256) {
        unsigned short v = u[i];
        int e = (v >> 7) & 0xFF;
        if (e > 133 || (e != 0 && e < 100)) wild++;
        else if (e == 0 && (v & 0x7F)) wild++;
    }
    atomicAdd(&cnt, wild);
    __syncthreads();
    if (threadIdx.x == 0) *flag = (cnt > 1024) ? 1 : 0;
}

// ========== MERGED projection (addr + tx in one dispatch) ==========
// blocks [0,GPA) = addr nodes, [GPA,GPA+GPT) = tx nodes. LMODE 0: layer-1
// (dtype-flagged global input, K=64). LMODE 1: layers 2/3 (addr = semantic
// combine(o_a1,o_a2,attn)+relu; tx = ws fp32 o_tx; K=32). H stored fp16
// (one 64B cacheline/row); dst-side attention dots stored fp32; block 0
// zeroes the 64-float semantic accumulator (replaces a memset dispatch).
template<int K, int LMODE>
__global__ __launch_bounds__(256) void k_proj2(
        const void* __restrict__ Xa, const void* __restrict__ Xt,
        const void* __restrict__ X2, const float* __restrict__ attn,
        const void* __restrict__ W, int wOffA, int wOffT,
        const void* __restrict__ B, int bOffA, int bOffT,
        unsigned short* __restrict__ Ha, unsigned short* __restrict__ Ht,
        const void* __restrict__ attD, int lBase,
        float* __restrict__ ad0, float* __restrict__ ad1, float* __restrict__ ad2,
        const int* __restrict__ flagp, float* __restrict__ zsem) {
    constexpr int XS = K + 4;
    __shared__ float Ws[K * 32];
    __shared__ float Xs[64 * XS];
    const int f32 = *flagp;
    const int t = threadIdx.x;
    if (blockIdx.x == 0 && t < 64) zsem[t] = 0.f;
    const bool isA = blockIdx.x < GPA;
    const int bb = isA ? (int)blockIdx.x : (int)blockIdx.x - GPA;
    const int N = isA ? NA : NT;
    const int wOff = isA ? wOffA : wOffT;
    const int bOff = isA ? bOffA : bOffT;
    for (int i = t; i < K * 32; i += 256) Ws[i] = ldf(W, wOff + i, f32);
    const long n0 = (long)bb * 64;
    constexpr int TOT4 = 64 * K / 4;
    if (LMODE == 1) {
        if (isA) {
            const float w0 = attn[0], w1 = attn[1];
            const float* A1 = (const float*)Xa;
            const float* A2 = (const float*)X2;
            for (int i = t; i < TOT4; i += 256) {
                int g = i * 4;
                int r = g / K, c = g & (K - 1);
                long gr = n0 + r; if (gr >= N) gr = N - 1;
                float4 va = *(const float4*)&A1[gr * K + c];
                float4 vb = *(const float4*)&A2[gr * K + c];
                float* dst = &Xs[r * XS + c];
                float v0 = w0 * va.x + w1 * vb.x;
                float v1 = w0 * va.y + w1 * vb.y;
                float v2 = w0 * va.z + w1 * vb.z;
                float v3 = w0 * va.w + w1 * vb.w;
                dst[0] = (v0 > 0.f) ? v0 : 0.f;
                dst[1] = (v1 > 0.f) ? v1 : 0.f;
                dst[2] = (v2 > 0.f) ? v2 : 0.f;
                dst[3] = (v3 > 0.f) ? v3 : 0.f;
            }
        } else {
            const float* Xf = (const float*)Xt;
            for (int i = t; i < TOT4; i += 256) {
                int g = i * 4;
                int r = g / K, c = g & (K - 1);
                long gr = n0 + r; if (gr >= N) gr = N - 1;
                float4 v = *(const float4*)&Xf[gr * K + c];
                float* dst = &Xs[r * XS + c];
                dst[0] = v.x; dst[1] = v.y; dst[2] = v.z; dst[3] = v.w;
            }
        }
    } else {
        const void* X = isA ? Xa : Xt;
        if (f32) {
            const float* Xf = (const float*)X;
            for (int i = t; i < TOT4; i += 256) {
                int g = i * 4;
                int r = g / K, c = g & (K - 1);
                long gr = n0 + r; if (gr >= N) gr = N - 1;
                float4 v = *(const float4*)&Xf[gr * K + c];
                float* dst = &Xs[r * XS + c];
                dst[0] = v.x; dst[1] = v.y; dst[2] = v.z; dst[3] = v.w;
            }
        } else {
            const unsigned short* Xh = (const unsigned short*)X;
            for (int i = t; i < TOT4; i += 256) {
                int g = i * 4;
                int r = g / K, c = g & (K - 1);
                long gr = n0 + r; if (gr >= N) gr = N - 1;
                ushort4 v = *(const ushort4*)&Xh[gr * K + c];
                float* dst = &Xs[r * XS + c];
                dst[0] = bf2f(v.x); dst[1] = bf2f(v.y); dst[2] = bf2f(v.z); dst[3] = bf2f(v.w);
            }
        }
    }
    __syncthreads();
    const int nl = t >> 2, cg = t & 3;
    const long n = n0 + nl;
    float acc[8];
#pragma unroll
    for (int j = 0; j < 8; j++) acc[j] = ldf(B, bOff + cg * 8 + j, f32);
#pragma unroll
    for (int k = 0; k < K; k += 4) {
        float4 xv = *(const float4*)&Xs[nl * XS + k];
        const float x0 = xv.x, x1 = xv.y, x2 = xv.z, x3 = xv.w;
        const float* w0 = &Ws[(k + 0) * 32 + cg * 8];
        const float* w1 = &Ws[(k + 1) * 32 + cg * 8];
        const float* w2 = &Ws[(k + 2) * 32 + cg * 8];
        const float* w3 = &Ws[(k + 3) * 32 + cg * 8];
#pragma unroll
        for (int j = 0; j < 8; j++)
            acc[j] += x0 * w0[j] + x1 * w1[j] + x2 * w2[j] + x3 * w3[j];
    }
    if (n < N) {
        // fp16 H row: 32 halves = 64 B = exactly one cacheline per node
        unsigned int u01 = (unsigned)f2h(acc[0]) | ((unsigned)f2h(acc[1]) << 16);
        unsigned int u23 = (unsigned)f2h(acc[2]) | ((unsigned)f2h(acc[3]) << 16);
        unsigned int u45 = (unsigned)f2h(acc[4]) | ((unsigned)f2h(acc[5]) << 16);
        unsigned int u67 = (unsigned)f2h(acc[6]) | ((unsigned)f2h(acc[7]) << 16);
        unsigned short* Hh = isA ? Ha : Ht;
        *(uint4*)&Hh[n * 32 + cg * 8] = make_uint4(u01, u23, u45, u67);
        const int b = lBase + cg * 8;
        float dP = 0.f, dQ = 0.f;
#pragma unroll
        for (int d = 0; d < 8; d++) {
            float x = acc[d];
            if (isA) {
                dP += x * ldf(attD, b + 32 + d, f32);   // TA dst (edge type 1)
                dQ += x * ldf(attD, b + 64 + d, f32);   // AA dst (edge type 2)
            } else {
                dP += x * ldf(attD, b + d, f32);        // AT dst (edge type 0)
            }
        }
        if (isA) { ad1[n * 4 + cg] = dP; ad2[n * 4 + cg] = dQ; }
        else     { ad0[n * 4 + cg] = dP; }
    }
}

// ================= binned CSR build =================
// Phase A: bin edges by dst>>9 into fixed-capacity slots. pack = (ldst<<18)|src.
__global__ __launch_bounds__(256) void k_bin(
        const int* __restrict__ eat_s, const int* __restrict__ eat_d,
        const int* __restrict__ eta_s, const int* __restrict__ eta_d,
        const int* __restrict__ eaa_s, const int* __restrict__ eaa_d,
        int* __restrict__ gcnt,
        int* __restrict__ slot_at, int* __restrict__ slot_ta, int* __restrict__ slot_aa) {
    __shared__ int hist[P_AT];   // max bins per relation
    int b = blockIdx.x, t = threadIdx.x;
    const int *src, *dst; int E, P, seg; int* slot;
    if (b < CB_AT)              { src = eat_s; dst = eat_d; E = E_AT; P = P_AT; seg = 0;            slot = slot_at; }
    else if (b < CB_AT + CB_TA) { b -= CB_AT;  src = eta_s; dst = eta_d; E = E_TA; P = P_TA; seg = P_AT;        slot = slot_ta; }
    else                        { b -= CB_AT + CB_TA; src = eaa_s; dst = eaa_d; E = E_AA; P = P_AA; seg = P_AT + P_TA; slot = slot_aa; }
    long e0 = (long)b * CHK;
    for (int i = t; i < P; i += 256) hist[i] = 0;
    __syncthreads();
    for (int k = 0; k < CHK; k += 256) {
        long e = e0 + k + t;
        if (e < E) atomicAdd(&hist[dst[e] >> 9], 1);
    }
    __syncthreads();
    // reserve runs: hist[i] becomes this block's base cursor within bin i
    for (int i = t; i < P; i += 256) {
        int v = hist[i];
        hist[i] = atomicAdd(&gcnt[seg + i], v);
    }
    __syncthreads();
    for (int k = 0; k < CHK; k += 256) {
        long e = e0 + k + t;
        if (e < E) {
            int d = dst[e];
            int bin = d >> 9;
            int pos = atomicAdd(&hist[bin], 1);
            slot[bin * CAP + pos] = ((d & 511) << 18) | src[e];
        }
    }
}

// Phase A2: exclusive-scan bin counts per relation -> bin bases; write off[N].
__global__ void k_binscan(const int* __restrict__ gcnt, int* __restrict__ bbase,
                          int* __restrict__ off_at, int* __restrict__ off_ta,
                          int* __restrict__ off_aa) {
    __shared__ int sa[512], sb[512];
    int t = threadIdx.x;  // 512 threads
    const int segs[4] = {0, P_AT, P_AT + P_TA, NBINS};
    for (int r = 0; r < 3; r++) {
        int s0 = segs[r], P = segs[r + 1] - s0;
        sa[t] = (t < P) ? gcnt[s0 + t] : 0;
        __syncthreads();
        int* in = sa; int* out = sb;
        for (int o = 1; o < 512; o <<= 1) {
            out[t] = in[t] + (t >= o ? in[t - o] : 0);
            __syncthreads();
            int* tmp = in; in = out; out = tmp;
        }
        if (t < P) bbase[s0 + t] = (t ? in[t - 1] : 0);
        __syncthreads();
    }
    if (t == 0) { off_at[NT] = E_AT; off_ta[NA] = E_TA; off_aa[NA] = E_AA; }
}

// Phase B: per-bin LDS counting sort -> exact CSR + off.
__global__ __launch_bounds__(256) void k_binsort(
        const int* __restrict__ gcnt, const int* __restrict__ bbase,
        const int* __restrict__ slot_at, const int* __restrict__ slot_ta,
        const int* __restrict__ slot_aa,
        int* __restrict__ off_at, int* __restrict__ off_ta, int* __restrict__ off_aa,
        int* __restrict__ csr_at, int* __restrict__ csr_ta, int* __restrict__ csr_aa) {
    __shared__ int sa[512], sb[512], cur[512];
    int b = blockIdx.x, t = threadIdx.x;
    const int* slot; int* off; int* csr; int N, bin, seg;
    if (b < P_AT)              { slot = slot_at; off = off_at; csr = csr_at; N = NT; bin = b;                seg = 0; }
    else if (b < P_AT + P_TA)  { slot = slot_ta; off = off_ta; csr = csr_ta; N = NA; bin = b - P_AT;         seg = P_AT; }
    else                       { slot = slot_aa; off = off_aa; csr = csr_aa; N = NA; bin = b - P_AT - P_TA;  seg = P_AT + P_TA; }
    const int cnt  = gcnt[seg + bin];
    const int base = bbase[seg + bin];
    const int* sp = &slot[bin * CAP];
    sa[t] = 0; sa[t + 256] = 0;
    __syncthreads();
    for (int i = t; i < cnt; i += 256) atomicAdd(&sa[sp[i] >> 18], 1);
    __syncthreads();
    int* in = sa; int* out = sb;
    for (int o = 1; o < 512; o <<= 1) {
        for (int i = t; i < 512; i += 256)
            out[i] = in[i] + (i >= o ? in[i - o] : 0);
        __syncthreads();
        int* tmp = in; in = out; out = tmp;
    }
    for (int i = t; i < 512; i += 256) {
        int excl = i ? in[i - 1] : 0;
        cur[i] = excl;
        int gd = bin * 512 + i;
        if (gd < N) off[gd] = base + excl;
    }
    __syncthreads();
    for (int i = t; i < cnt; i += 256) {
        int pk = sp[i];
        int pos = atomicAdd(&cur[pk >> 18], 1);
        csr[base + pos] = pk & 0x3FFFF;
    }
}

// ========== tri-relation gather: 8 lanes/dst, fp16 H, in-kernel src alpha ==========
__global__ __launch_bounds__(256) void k_gather3(
        const int* __restrict__ off_at, const int* __restrict__ csr_at,
        const int* __restrict__ off_ta, const int* __restrict__ csr_ta,
        const int* __restrict__ off_aa, const int* __restrict__ csr_aa,
        const float* __restrict__ ad0, const float* __restrict__ ad1,
        const float* __restrict__ ad2,
        const unsigned short* __restrict__ h_a, const unsigned short* __restrict__ h_t,
        float* __restrict__ o_tx, float* __restrict__ o_a1, float* __restrict__ o_a2,
        const void* __restrict__ attS, int lBase, const int* __restrict__ flagp) {
    int b = blockIdx.x;
    const int *off, *csr;
    const float *ad_;
    const unsigned short* Hs;
    float* O;
    int N, attOff;
    if (b < GB_AT) {
        off = off_at; csr = csr_at; ad_ = ad0; Hs = h_a; O = o_tx; N = NT;
        attOff = lBase;            // edge type 0 (A->T)
    } else if (b < GB_AT + GB_TA) {
        b -= GB_AT;
        off = off_ta; csr = csr_ta; ad_ = ad1; Hs = h_t; O = o_a1; N = NA;
        attOff = lBase + 32;       // edge type 1 (T->A)
    } else {
        b -= GB_AT + GB_TA;
        off = off_aa; csr = csr_aa; ad_ = ad2; Hs = h_a; O = o_a2; N = NA;
        attOff = lBase + 64;       // edge type 2 (A->A)
    }
    const int t = threadIdx.x;
    const int q = t & 7;          // column quad 0..7
    const int hh = q >> 1;        // head
    const int n = b * 32 + (t >> 3);
    if (n >= N) return;
    const int f32 = *flagp;
    const float aq0 = ldf(attS, attOff + q * 4 + 0, f32);
    const float aq1 = ldf(attS, attOff + q * 4 + 1, f32);
    const float aq2 = ldf(attS, attOff + q * 4 + 2, f32);
    const float aq3 = ldf(attS, attOff + q * 4 + 3, f32);
    const float adv = ad_[n * 4 + hh];
    const int p0 = off[n], p1 = off[n + 1];
    float ax = 0.f, ay = 0.f, az = 0.f, aw = 0.f, se = 0.f;
    int p = p0;
    for (; p + 4 <= p1; p += 4) {
        int s0 = csr[p], s1 = csr[p + 1], s2 = csr[p + 2], s3 = csr[p + 3];
        ushort4 v0 = *(const ushort4*)&Hs[s0 * 32 + q * 4];
        ushort4 v1 = *(const ushort4*)&Hs[s1 * 32 + q * 4];
        ushort4 v2 = *(const ushort4*)&Hs[s2 * 32 + q * 4];
        ushort4 v3 = *(const ushort4*)&Hs[s3 * 32 + q * 4];
        float h00 = h2f(v0.x), h01 = h2f(v0.y), h02 = h2f(v0.z), h03 = h2f(v0.w);
        float h10 = h2f(v1.x), h11 = h2f(v1.y), h12 = h2f(v1.z), h13 = h2f(v1.w);
        float h20 = h2f(v2.x), h21 = h2f(v2.y), h22 = h2f(v2.z), h23 = h2f(v2.w);
        float h30 = h2f(v3.x), h31 = h2f(v3.y), h32 = h2f(v3.z), h33 = h2f(v3.w);
        float pt0 = h00 * aq0 + h01 * aq1 + h02 * aq2 + h03 * aq3;
        float pt1 = h10 * aq0 + h11 * aq1 + h12 * aq2 + h13 * aq3;
        float pt2 = h20 * aq0 + h21 * aq1 + h22 * aq2 + h23 * aq3;
        float pt3 = h30 * aq0 + h31 * aq1 + h32 * aq2 + h33 * aq3;
        float al0 = pt0 + __shfl_xor(pt0, 1);
        float al1 = pt1 + __shfl_xor(pt1, 1);
        float al2 = pt2 + __shfl_xor(pt2, 1);
        float al3 = pt3 + __shfl_xor(pt3, 1);
        float l0 = al0 + adv; l0 = fmaxf(l0, 0.2f * l0); float e0 = __expf(l0);
        float l1 = al1 + adv; l1 = fmaxf(l1, 0.2f * l1); float e1 = __expf(l1);
        float l2 = al2 + adv; l2 = fmaxf(l2, 0.2f * l2); float e2 = __expf(l2);
        float l3 = al3 + adv; l3 = fmaxf(l3, 0.2f * l3); float e3 = __expf(l3);
        se += e0 + e1 + e2 + e3;
        ax += e0 * h00 + e1 * h10 + e2 * h20 + e3 * h30;
        ay += e0 * h01 + e1 * h11 + e2 * h21 + e3 * h31;
        az += e0 * h02 + e1 * h12 + e2 * h22 + e3 * h32;
        aw += e0 * h03 + e1 * h13 + e2 * h23 + e3 * h33;
    }
    for (; p < p1; p++) {
        int s = csr[p];
        ushort4 v = *(const ushort4*)&Hs[s * 32 + q * 4];
        float h0 = h2f(v.x), h1 = h2f(v.y), h2 = h2f(v.z), h3 = h2f(v.w);
        float pt = h0 * aq0 + h1 * aq1 + h2 * aq2 + h3 * aq3;
        float al = pt + __shfl_xor(pt, 1);
        float l = al + adv; l = fmaxf(l, 0.2f * l);
        float e = __expf(l);
        se += e;
        ax += e * h0; ay += e * h1; az += e * h2; aw += e * h3;
    }
    const float inv = 1.f / (se + 1e-16f);
    float4 r;
    r.x = fmaxf(ax * inv, 0.f);
    r.y = fmaxf(ay * inv, 0.f);
    r.z = fmaxf(az * inv, 0.f);
    r.w = fmaxf(aw * inv, 0.f);
    *(float4*)&O[n * 32 + q * 4] = r;
}

// ---------- semantic reduce: one relation per block (2x grid for latency) ----------
__global__ __launch_bounds__(256) void k_sem_reduce2(
        const float* __restrict__ O1, const float* __restrict__ O2,
        const void* __restrict__ kWp, int kwOff,
        const void* __restrict__ kbp, int kbOff,
        float* __restrict__ accum, const int* __restrict__ flagp) {
    int f32 = *flagp;
    __shared__ float w[1056];
    __shared__ float sacc[32];
    const int r = (blockIdx.x >= NB_SEM) ? 1 : 0;
    const float* O = r ? O2 : O1;
    for (int i = threadIdx.x; i < 1024; i += 256) w[i] = ldf(kWp, kwOff + i, f32);
    if (threadIdx.x < 32) {
        w[1024 + threadIdx.x] = ldf(kbp, kbOff + threadIdx.x, f32);
        sacc[threadIdx.x] = 0.f;
    }
    __syncthreads();
    long n = (long)(blockIdx.x - r * NB_SEM) * 256 + threadIdx.x;
    float y[32];
    if (n < NA) {
        float x[32];
#pragma unroll
        for (int k = 0; k < 32; k++) x[k] = O[n * 32 + k];
#pragma unroll
        for (int f = 0; f < 32; f++) {
            float acc = w[1024 + f];
#pragma unroll
            for (int k = 0; k < 32; k++) acc += x[k] * w[k * 32 + f];
            y[f] = ftanh(acc);
        }
    } else {
#pragma unroll
        for (int f = 0; f < 32; f++) y[f] = 0.f;
    }
#pragma unroll
    for (int f = 0; f < 32; f++) {
        float v = y[f];
        for (int o = 32; o > 0; o >>= 1) v += __shfl_xor(v, o, 64);
        if ((threadIdx.x & 63) == 0) atomicAdd(&sacc[f], v);
    }
    __syncthreads();
    if (threadIdx.x < 32) atomicAdd(&accum[r * 32 + threadIdx.x], sacc[threadIdx.x]);
}

__global__ void k_sem_attn(const float* __restrict__ accum, float Ninv,
                           const void* __restrict__ q, int qOff,
                           float* __restrict__ attn, const int* __restrict__ flagp) {
    if (threadIdx.x == 0) {
        int f32 = *flagp;
        float s0 = 0.f, s1 = 0.f;
        for (int f = 0; f < 32; f++) {
            float qf = ldf(q, qOff + f, f32);
            s0 += accum[f] * Ninv * qf;
            s1 += accum[32 + f] * Ninv * qf;
        }
        float m = fmaxf(s0, s1);
        float e0 = __expf(s0 - m), e1 = __expf(s1 - m);
        float inv = 1.f / (e0 + e1);
        attn[0] = e0 * inv;
        attn[1] = e1 * inv;
    }
}

// ---------- fused combine + final linear (layer 3 only) ----------
__global__ void k_combine_final(const float* __restrict__ o1, const float* __restrict__ o2,
                                const float* __restrict__ attn,
                                const void* __restrict__ linW, const void* __restrict__ linb,
                                void* __restrict__ out, int N, const int* __restrict__ flagp) {
    int n = blockIdx.x * blockDim.x + threadIdx.x;
    if (n >= N) return;
    int f32 = *flagp;
    float w0 = attn[0], w1 = attn[1];
    float s0 = ldf(linb, 0, f32), s1 = ldf(linb, 1, f32);
    const float* p1 = &o1[(long)n * 32];
    const float* p2 = &o2[(long)n * 32];
#pragma unroll
    for (int f = 0; f < 32; f++) {
        float v = w0 * p1[f] + w1 * p2[f];
        v = (v > 0.f) ? v : 0.f;
        s0 += v * ldf(linW, f * 2, f32);
        s1 += v * ldf(linW, f * 2 + 1, f32);
    }
    if (f32) { ((float*)out)[n * 2] = s0; ((float*)out)[n * 2 + 1] = s1; }
    else {
        ((__hip_bfloat16*)out)[n * 2] = __float2bfloat16(s0);
        ((__hip_bfloat16*)out)[n * 2 + 1] = __float2bfloat16(s1);
    }
}

static inline int gblocks(long n) { return (int)((n + 255) / 256); }

extern "C" void kernel_launch(void* const* d_in, const int* in_sizes, int n_in,
                              void* d_out, int out_size, void* d_ws, size_t ws_size,
                              hipStream_t stream) {
    const void* x_addr = d_in[0];
    const void* x_tx   = d_in[1];
    const int* eat_s = (const int*)d_in[2];
    const int* eat_d = (const int*)d_in[3];
    const int* eta_s = (const int*)d_in[4];
    const int* eta_d = (const int*)d_in[5];
    const int* eaa_s = (const int*)d_in[6];
    const int* eaa_d = (const int*)d_in[7];
    const void* pW1  = d_in[8];
    const void* pb1  = d_in[9];
    const void* pW23 = d_in[10];
    const void* pb23 = d_in[11];
    const void* attS = d_in[12];
    const void* attD = d_in[13];
    const void* kW   = d_in[14];
    const void* kb   = d_in[15];
    const void* qv   = d_in[16];
    const void* linW = d_in[17];
    const void* linb = d_in[18];

    const size_t NA32 = (size_t)NA * 32, NT32 = (size_t)NT * 32;
    const size_t NA4 = (size_t)NA * 4, NT4 = (size_t)NT * 4;

    float* ws    = (float*)d_ws;
    float* h_aF  = ws;                   // fp16 rows (uses half the slot)
    float* h_tF  = h_aF + NA32;
    float* o_a1  = h_tF + NT32;
    float* o_a2  = o_a1 + NA32;
    float* o_tx  = o_a2 + NA32;
    float* ad1   = o_tx + NT32;          // TA dst alphas (addr)
    float* ad2   = ad1 + NA4;            // AA dst alphas (addr)
    float* ad0   = ad2 + NA4;            // AT dst alphas (tx)
    float* sem   = ad0 + NT4;            // 64 accum + 2 attn
    int*   flagp = (int*)(sem + 66);
    int*   off_at = flagp + 16;          // NT+1
    int*   off_ta = off_at + (NT + 1);   // NA+1
    int*   off_aa = off_ta + (NA + 1);   // NA+1
    int*   csr_at = off_aa + (NA + 1);   // E_AT
    int*   csr_ta = csr_at + E_AT;       // E_TA
    int*   csr_aa = csr_ta + E_TA;       // E_AA
    int*   gcnt   = csr_aa + E_AA;       // 1024
    int*   bbase  = gcnt + 1024;         // 1024
    int*   slot_at = bbase + 1024;       // P_AT*CAP
    int*   slot_ta = slot_at + P_AT * CAP;
    int*   slot_aa = slot_ta + P_TA * CAP;

    unsigned short* h_a = (unsigned short*)h_aF;
    unsigned short* h_t = (unsigned short*)h_tF;

    k_detect<<<1, 256, 0, stream>>>(x_addr, flagp);

    // ---- binned CSR build ----
    (void)hipMemsetAsync(gcnt, 0, 1024 * sizeof(int), stream);
    k_bin<<<CB_AT + CB_TA + CB_AA, 256, 0, stream>>>(
        eat_s, eat_d, eta_s, eta_d, eaa_s, eaa_d, gcnt, slot_at, slot_ta, slot_aa);
    k_binscan<<<1, 512, 0, stream>>>(gcnt, bbase, off_at, off_ta, off_aa);
    k_binsort<<<NBINS, 256, 0, stream>>>(gcnt, bbase, slot_at, slot_ta, slot_aa,
                                         off_at, off_ta, off_aa, csr_at, csr_ta, csr_aa);

    for (int l = 0; l < 3; l++) {
        if (l == 0) {
            k_proj2<64, 0><<<GPA + GPT, 256, 0, stream>>>(
                x_addr, x_tx, nullptr, nullptr,
                pW1, 0, 2048, pb1, 0, 32,
                h_a, h_t, attD, 0, ad0, ad1, ad2, flagp, sem);
        } else {
            int wi = (l - 1) * 2;
            k_proj2<32, 1><<<GPA + GPT, 256, 0, stream>>>(
                o_a1, o_tx, o_a2, sem + 64,
                pW23, (wi + 0) * 1024, (wi + 1) * 1024,
                pb23, (wi + 0) * 32, (wi + 1) * 32,
                h_a, h_t, attD, l * 96, ad0, ad1, ad2, flagp, sem);
        }
        k_gather3<<<GB_AT + GB_TA + GB_AA, 256, 0, stream>>>(
            off_at, csr_at, off_ta, csr_ta, off_aa, csr_aa,
            ad0, ad1, ad2, h_a, h_t, o_tx, o_a1, o_a2, attS, l * 96, flagp);
        k_sem_reduce2<<<2 * NB_SEM, 256, 0, stream>>>(o_a1, o_a2, kW, l * 1024, kb, l * 32,
                                                      sem, flagp);
        k_sem_attn<<<1, 64, 0, stream>>>(sem, 1.0f / NA, qv, l * 32, sem + 64, flagp);
        if (l == 2) {
            k_combine_final<<<gblocks(NA), 256, 0, stream>>>(o_a1, o_a2, sem + 64,
                                                             linW, linb, d_out, NA, flagp);
        }
    }
}

// Round 5
// 691.113 us; speedup vs baseline: 1.5006x; 1.0755x over previous
//
#include <hip/hip_runtime.h>
#include <hip/hip_bf16.h>
#include <hip/hip_fp16.h>

#define NA 150000
#define NT 200000
#define E_AT 1000000
#define E_TA 1000000
#define E_AA 500000

#define CHK 2048           // edges per k_bin block
#define CAP 8192           // slot capacity per bin (max bin count ~3.8K)
#define P_AT 391           // ceil(NT/512)
#define P_TA 293           // ceil(NA/512)
#define P_AA 293
#define NBINS (P_AT + P_TA + P_AA)   // 977
#define CB_AT 489          // ceil(E_AT/CHK)
#define CB_TA 489
#define CB_AA 245

// gather grid partition: 32 dsts per 256-thread block (8 lanes per dst)
#define GB_AT 6250         // ceil(NT/32)
#define GB_TA 4688         // ceil(NA/32)
#define GB_AA 4688

// proj grid partition: 64 nodes per 64-thread block (thread-per-node)
#define GPA 2344           // ceil(NA/64)
#define GPT 3125           // NT/64
#define NB_SEM 586         // ceil(NA/256) blocks per relation for sem reduce

// fp32 weight cache offsets (in ws)
#define WO_W1   0          // 2*64*32 = 4096
#define WO_B1   4096       // 64
#define WO_W23  4160       // 4096
#define WO_B23  8256       // 128
#define WO_AS   8384       // 288
#define WO_AD   8672       // 288
#define WO_KW   8960       // 3072
#define WO_KB   12032      // 96
#define WO_Q    12128      // 96
#define WO_LW   12224      // 64
#define WO_LB   12288      // 2
#define WT_TOT  12290

// ---------- dtype-flexible load: flag==1 -> fp32, flag==0 -> bf16 ----------
__device__ __forceinline__ float ldf(const void* p, long i, int f32) {
    if (f32) return ((const float*)p)[i];
    unsigned int u = ((const unsigned short*)p)[i];
    union { unsigned int ui; float f; } v; v.ui = u << 16;
    return v.f;
}
__device__ __forceinline__ float bf2f(unsigned short u) {
    union { unsigned int ui; float f; } v; v.ui = ((unsigned int)u) << 16;
    return v.f;
}
__device__ __forceinline__ float h2f(unsigned short u) {
    return __half2float(__ushort_as_half(u));
}
__device__ __forceinline__ unsigned short f2h(float x) {
    return __half_as_ushort(__float2half(x));
}
__device__ __forceinline__ float ftanh(float x) {
    x = fminf(fmaxf(x, -9.f), 9.f);
    float e = __expf(2.f * x);
    return (e - 1.f) / (e + 1.f);
}

// ---------- detect fp32 (1) vs bf16 (0) float inputs ----------
__global__ void k_detect(const void* __restrict__ x, int* __restrict__ flag) {
    __shared__ int cnt;
    if (threadIdx.x == 0) cnt = 0;
    __syncthreads();
    const unsigned short* u = (const unsigned short*)x;
    int wild = 0;
    for (int i = threadIdx.x; i < 4096; i += 256) {
        unsigned short v = u[i];
        int e = (v >> 7) & 0xFF;
        if (e > 133 || (e != 0 && e < 100)) wild++;
        else if (e == 0 && (v & 0x7F)) wild++;
    }
    atomicAdd(&cnt, wild);
    __syncthreads();
    if (threadIdx.x == 0) *flag = (cnt > 1024) ? 1 : 0;
}

// ---------- one-time weight conversion to fp32 cache ----------
__global__ void k_cvtw(const void* __restrict__ pW1, const void* __restrict__ pb1,
                       const void* __restrict__ pW23, const void* __restrict__ pb23,
                       const void* __restrict__ attS, const void* __restrict__ attD,
                       const void* __restrict__ kW, const void* __restrict__ kb,
                       const void* __restrict__ qv, const void* __restrict__ linW,
                       const void* __restrict__ linb,
                       float* __restrict__ wts, const int* __restrict__ flagp) {
    const int f32 = *flagp;
    const int t = threadIdx.x;
    for (int i = t; i < 4096; i += 256) wts[WO_W1 + i]  = ldf(pW1, i, f32);
    for (int i = t; i < 64;   i += 256) wts[WO_B1 + i]  = ldf(pb1, i, f32);
    for (int i = t; i < 4096; i += 256) wts[WO_W23 + i] = ldf(pW23, i, f32);
    for (int i = t; i < 128;  i += 256) wts[WO_B23 + i] = ldf(pb23, i, f32);
    for (int i = t; i < 288;  i += 256) wts[WO_AS + i]  = ldf(attS, i, f32);
    for (int i = t; i < 288;  i += 256) wts[WO_AD + i]  = ldf(attD, i, f32);
    for (int i = t; i < 3072; i += 256) wts[WO_KW + i]  = ldf(kW, i, f32);
    for (int i = t; i < 96;   i += 256) wts[WO_KB + i]  = ldf(kb, i, f32);
    for (int i = t; i < 96;   i += 256) wts[WO_Q + i]   = ldf(qv, i, f32);
    for (int i = t; i < 64;   i += 256) wts[WO_LW + i]  = ldf(linW, i, f32);
    for (int i = t; i < 2;    i += 256) wts[WO_LB + i]  = ldf(linb, i, f32);
}

// ========== projection: thread-per-node, W in SGPRs (wave-uniform s_load) ==========
// 64-thread block = 64 nodes. X staged to LDS (ldim K+1 -> conflict-free
// ds_read_b32). Each thread computes its node's full 32-dim output in regs:
// per k: 1 LDS read + 32 FMAs with scalar W operand -> VALU-bound at the FMA
// floor instead of LDS-latency-bound. Epilogue (H fp16 row, attD dots) is
// thread-local, no cross-lane ops. blocks [0,GPA)=addr, [GPA,GPA+GPT)=tx.
// LMODE 0: layer-1 (dtype-flagged input). LMODE 1: addr=combine(o1,o2,attn)+relu,
// tx=fp32 o_tx. Block 0 zeroes the 64-float semantic accumulator.
template<int K, int LMODE>
__global__ __launch_bounds__(64, 4) void k_proj2(
        const void* __restrict__ Xa, const void* __restrict__ Xt,
        const void* __restrict__ X2, const float* __restrict__ attn,
        const float* __restrict__ W, int wOffA, int wOffT,
        const float* __restrict__ Bv, int bOffA, int bOffT,
        unsigned short* __restrict__ Ha, unsigned short* __restrict__ Ht,
        const float* __restrict__ attD, int lBase,
        float* __restrict__ ad0, float* __restrict__ ad1, float* __restrict__ ad2,
        const int* __restrict__ flagp, float* __restrict__ zsem) {
    constexpr int XS = K + 1;
    __shared__ float Xs[64 * XS];
    const int t = threadIdx.x;
    if (blockIdx.x == 0) zsem[t] = 0.f;
    const bool isA = blockIdx.x < GPA;
    const int bb = isA ? (int)blockIdx.x : (int)blockIdx.x - GPA;
    const int N = isA ? NA : NT;
    const int wOff = isA ? wOffA : wOffT;
    const int bOff = isA ? bOffA : bOffT;
    const long n0 = (long)bb * 64;
    constexpr int CPR = K / 4;         // float4 chunks per row
    constexpr int TOT4 = 64 * CPR;
    if (LMODE == 1) {
        if (isA) {
            const float w0 = attn[0], w1 = attn[1];
            const float* A1 = (const float*)Xa;
            const float* A2 = (const float*)X2;
            for (int i = t; i < TOT4; i += 64) {
                int r = i / CPR, c = (i - r * CPR) * 4;
                long gr = n0 + r; if (gr >= N) gr = N - 1;
                float4 va = *(const float4*)&A1[gr * K + c];
                float4 vb = *(const float4*)&A2[gr * K + c];
                float* d = &Xs[r * XS + c];
                float v0 = w0 * va.x + w1 * vb.x;
                float v1 = w0 * va.y + w1 * vb.y;
                float v2 = w0 * va.z + w1 * vb.z;
                float v3 = w0 * va.w + w1 * vb.w;
                d[0] = (v0 > 0.f) ? v0 : 0.f;
                d[1] = (v1 > 0.f) ? v1 : 0.f;
                d[2] = (v2 > 0.f) ? v2 : 0.f;
                d[3] = (v3 > 0.f) ? v3 : 0.f;
            }
        } else {
            const float* Xf = (const float*)Xt;
            for (int i = t; i < TOT4; i += 64) {
                int r = i / CPR, c = (i - r * CPR) * 4;
                long gr = n0 + r; if (gr >= N) gr = N - 1;
                float4 v = *(const float4*)&Xf[gr * K + c];
                float* d = &Xs[r * XS + c];
                d[0] = v.x; d[1] = v.y; d[2] = v.z; d[3] = v.w;
            }
        }
    } else {
        const void* X = isA ? Xa : Xt;
        const int f32 = *flagp;
        if (f32) {
            const float* Xf = (const float*)X;
            for (int i = t; i < TOT4; i += 64) {
                int r = i / CPR, c = (i - r * CPR) * 4;
                long gr = n0 + r; if (gr >= N) gr = N - 1;
                float4 v = *(const float4*)&Xf[gr * K + c];
                float* d = &Xs[r * XS + c];
                d[0] = v.x; d[1] = v.y; d[2] = v.z; d[3] = v.w;
            }
        } else {
            const unsigned short* Xh = (const unsigned short*)X;
            for (int i = t; i < TOT4; i += 64) {
                int r = i / CPR, c = (i - r * CPR) * 4;
                long gr = n0 + r; if (gr >= N) gr = N - 1;
                ushort4 v = *(const ushort4*)&Xh[gr * K + c];
                float* d = &Xs[r * XS + c];
                d[0] = bf2f(v.x); d[1] = bf2f(v.y); d[2] = bf2f(v.z); d[3] = bf2f(v.w);
            }
        }
    }
    __syncthreads();
    float acc[32];
#pragma unroll
    for (int j = 0; j < 32; j++) acc[j] = Bv[bOff + j];
    const float* wp = W + wOff;
#pragma unroll 2
    for (int k = 0; k < K; k++) {
        float x = Xs[t * XS + k];
#pragma unroll
        for (int j = 0; j < 32; j++) acc[j] = fmaf(x, wp[k * 32 + j], acc[j]);
    }
    const long n = n0 + t;
    if (n < N) {
        unsigned short* Hh = isA ? Ha : Ht;
        unsigned int pk[16];
#pragma unroll
        for (int j = 0; j < 16; j++)
            pk[j] = (unsigned)f2h(acc[2 * j]) | ((unsigned)f2h(acc[2 * j + 1]) << 16);
        uint4* dst = (uint4*)&Hh[n * 32];
        dst[0] = make_uint4(pk[0], pk[1], pk[2], pk[3]);
        dst[1] = make_uint4(pk[4], pk[5], pk[6], pk[7]);
        dst[2] = make_uint4(pk[8], pk[9], pk[10], pk[11]);
        dst[3] = make_uint4(pk[12], pk[13], pk[14], pk[15]);
        if (isA) {
            float r1[4], r2[4];
#pragma unroll
            for (int h = 0; h < 4; h++) {
                float s1 = 0.f, s2 = 0.f;
#pragma unroll
                for (int d = 0; d < 8; d++) {
                    float x = acc[h * 8 + d];
                    s1 += x * attD[lBase + 32 + h * 8 + d];
                    s2 += x * attD[lBase + 64 + h * 8 + d];
                }
                r1[h] = s1; r2[h] = s2;
            }
            *(float4*)&ad1[n * 4] = make_float4(r1[0], r1[1], r1[2], r1[3]);
            *(float4*)&ad2[n * 4] = make_float4(r2[0], r2[1], r2[2], r2[3]);
        } else {
            float r0[4];
#pragma unroll
            for (int h = 0; h < 4; h++) {
                float s0 = 0.f;
#pragma unroll
                for (int d = 0; d < 8; d++)
                    s0 += acc[h * 8 + d] * attD[lBase + h * 8 + d];
                r0[h] = s0;
            }
            *(float4*)&ad0[n * 4] = make_float4(r0[0], r0[1], r0[2], r0[3]);
        }
    }
}

// ================= binned CSR build =================
// Phase A: bin edges by dst>>9 into fixed-capacity slots. pack = (ldst<<18)|src.
__global__ __launch_bounds__(256) void k_bin(
        const int* __restrict__ eat_s, const int* __restrict__ eat_d,
        const int* __restrict__ eta_s, const int* __restrict__ eta_d,
        const int* __restrict__ eaa_s, const int* __restrict__ eaa_d,
        int* __restrict__ gcnt,
        int* __restrict__ slot_at, int* __restrict__ slot_ta, int* __restrict__ slot_aa) {
    __shared__ int hist[P_AT];   // max bins per relation
    int b = blockIdx.x, t = threadIdx.x;
    const int *src, *dst; int E, P, seg; int* slot;
    if (b < CB_AT)              { src = eat_s; dst = eat_d; E = E_AT; P = P_AT; seg = 0;            slot = slot_at; }
    else if (b < CB_AT + CB_TA) { b -= CB_AT;  src = eta_s; dst = eta_d; E = E_TA; P = P_TA; seg = P_AT;        slot = slot_ta; }
    else                        { b -= CB_AT + CB_TA; src = eaa_s; dst = eaa_d; E = E_AA; P = P_AA; seg = P_AT + P_TA; slot = slot_aa; }
    long e0 = (long)b * CHK;
    for (int i = t; i < P; i += 256) hist[i] = 0;
    __syncthreads();
    for (int k = 0; k < CHK; k += 256) {
        long e = e0 + k + t;
        if (e < E) atomicAdd(&hist[dst[e] >> 9], 1);
    }
    __syncthreads();
    // reserve runs: hist[i] becomes this block's base cursor within bin i
    for (int i = t; i < P; i += 256) {
        int v = hist[i];
        hist[i] = atomicAdd(&gcnt[seg + i], v);
    }
    __syncthreads();
    for (int k = 0; k < CHK; k += 256) {
        long e = e0 + k + t;
        if (e < E) {
            int d = dst[e];
            int bin = d >> 9;
            int pos = atomicAdd(&hist[bin], 1);
            slot[bin * CAP + pos] = ((d & 511) << 18) | src[e];
        }
    }
}

// Phase A2: exclusive-scan bin counts per relation -> bin bases; write off[N].
__global__ void k_binscan(const int* __restrict__ gcnt, int* __restrict__ bbase,
                          int* __restrict__ off_at, int* __restrict__ off_ta,
                          int* __restrict__ off_aa) {
    __shared__ int sa[512], sb[512];
    int t = threadIdx.x;  // 512 threads
    const int segs[4] = {0, P_AT, P_AT + P_TA, NBINS};
    for (int r = 0; r < 3; r++) {
        int s0 = segs[r], P = segs[r + 1] - s0;
        sa[t] = (t < P) ? gcnt[s0 + t] : 0;
        __syncthreads();
        int* in = sa; int* out = sb;
        for (int o = 1; o < 512; o <<= 1) {
            out[t] = in[t] + (t >= o ? in[t - o] : 0);
            __syncthreads();
            int* tmp = in; in = out; out = tmp;
        }
        if (t < P) bbase[s0 + t] = (t ? in[t - 1] : 0);
        __syncthreads();
    }
    if (t == 0) { off_at[NT] = E_AT; off_ta[NA] = E_TA; off_aa[NA] = E_AA; }
}

// Phase B: per-bin LDS counting sort -> exact CSR + off.
__global__ __launch_bounds__(256) void k_binsort(
        const int* __restrict__ gcnt, const int* __restrict__ bbase,
        const int* __restrict__ slot_at, const int* __restrict__ slot_ta,
        const int* __restrict__ slot_aa,
        int* __restrict__ off_at, int* __restrict__ off_ta, int* __restrict__ off_aa,
        int* __restrict__ csr_at, int* __restrict__ csr_ta, int* __restrict__ csr_aa) {
    __shared__ int sa[512], sb[512], cur[512];
    int b = blockIdx.x, t = threadIdx.x;
    const int* slot; int* off; int* csr; int N, bin, seg;
    if (b < P_AT)              { slot = slot_at; off = off_at; csr = csr_at; N = NT; bin = b;                seg = 0; }
    else if (b < P_AT + P_TA)  { slot = slot_ta; off = off_ta; csr = csr_ta; N = NA; bin = b - P_AT;         seg = P_AT; }
    else                       { slot = slot_aa; off = off_aa; csr = csr_aa; N = NA; bin = b - P_AT - P_TA;  seg = P_AT + P_TA; }
    const int cnt  = gcnt[seg + bin];
    const int base = bbase[seg + bin];
    const int* sp = &slot[bin * CAP];
    sa[t] = 0; sa[t + 256] = 0;
    __syncthreads();
    for (int i = t; i < cnt; i += 256) atomicAdd(&sa[sp[i] >> 18], 1);
    __syncthreads();
    int* in = sa; int* out = sb;
    for (int o = 1; o < 512; o <<= 1) {
        for (int i = t; i < 512; i += 256)
            out[i] = in[i] + (i >= o ? in[i - o] : 0);
        __syncthreads();
        int* tmp = in; in = out; out = tmp;
    }
    for (int i = t; i < 512; i += 256) {
        int excl = i ? in[i - 1] : 0;
        cur[i] = excl;
        int gd = bin * 512 + i;
        if (gd < N) off[gd] = base + excl;
    }
    __syncthreads();
    for (int i = t; i < cnt; i += 256) {
        int pk = sp[i];
        int pos = atomicAdd(&cur[pk >> 18], 1);
        csr[base + pos] = pk & 0x3FFFF;
    }
}

// ========== tri-relation gather: 8 lanes/dst, fp16 H, in-kernel src alpha ==========
__global__ __launch_bounds__(256) void k_gather3(
        const int* __restrict__ off_at, const int* __restrict__ csr_at,
        const int* __restrict__ off_ta, const int* __restrict__ csr_ta,
        const int* __restrict__ off_aa, const int* __restrict__ csr_aa,
        const float* __restrict__ ad0, const float* __restrict__ ad1,
        const float* __restrict__ ad2,
        const unsigned short* __restrict__ h_a, const unsigned short* __restrict__ h_t,
        float* __restrict__ o_tx, float* __restrict__ o_a1, float* __restrict__ o_a2,
        const float* __restrict__ attS, int lBase) {
    int b = blockIdx.x;
    const int *off, *csr;
    const float *ad_;
    const unsigned short* Hs;
    float* O;
    int N, attOff;
    if (b < GB_AT) {
        off = off_at; csr = csr_at; ad_ = ad0; Hs = h_a; O = o_tx; N = NT;
        attOff = lBase;            // edge type 0 (A->T)
    } else if (b < GB_AT + GB_TA) {
        b -= GB_AT;
        off = off_ta; csr = csr_ta; ad_ = ad1; Hs = h_t; O = o_a1; N = NA;
        attOff = lBase + 32;       // edge type 1 (T->A)
    } else {
        b -= GB_AT + GB_TA;
        off = off_aa; csr = csr_aa; ad_ = ad2; Hs = h_a; O = o_a2; N = NA;
        attOff = lBase + 64;       // edge type 2 (A->A)
    }
    const int t = threadIdx.x;
    const int q = t & 7;          // column quad 0..7
    const int hh = q >> 1;        // head
    const int n = b * 32 + (t >> 3);
    if (n >= N) return;
    const float4 aq = *(const float4*)&attS[attOff + q * 4];
    const float aq0 = aq.x, aq1 = aq.y, aq2 = aq.z, aq3 = aq.w;
    const float adv = ad_[n * 4 + hh];
    const int p0 = off[n], p1 = off[n + 1];
    float ax = 0.f, ay = 0.f, az = 0.f, aw = 0.f, se = 0.f;
    int p = p0;
    for (; p + 4 <= p1; p += 4) {
        int s0 = csr[p], s1 = csr[p + 1], s2 = csr[p + 2], s3 = csr[p + 3];
        ushort4 v0 = *(const ushort4*)&Hs[s0 * 32 + q * 4];
        ushort4 v1 = *(const ushort4*)&Hs[s1 * 32 + q * 4];
        ushort4 v2 = *(const ushort4*)&Hs[s2 * 32 + q * 4];
        ushort4 v3 = *(const ushort4*)&Hs[s3 * 32 + q * 4];
        float h00 = h2f(v0.x), h01 = h2f(v0.y), h02 = h2f(v0.z), h03 = h2f(v0.w);
        float h10 = h2f(v1.x), h11 = h2f(v1.y), h12 = h2f(v1.z), h13 = h2f(v1.w);
        float h20 = h2f(v2.x), h21 = h2f(v2.y), h22 = h2f(v2.z), h23 = h2f(v2.w);
        float h30 = h2f(v3.x), h31 = h2f(v3.y), h32 = h2f(v3.z), h33 = h2f(v3.w);
        float pt0 = h00 * aq0 + h01 * aq1 + h02 * aq2 + h03 * aq3;
        float pt1 = h10 * aq0 + h11 * aq1 + h12 * aq2 + h13 * aq3;
        float pt2 = h20 * aq0 + h21 * aq1 + h22 * aq2 + h23 * aq3;
        float pt3 = h30 * aq0 + h31 * aq1 + h32 * aq2 + h33 * aq3;
        float al0 = pt0 + __shfl_xor(pt0, 1);
        float al1 = pt1 + __shfl_xor(pt1, 1);
        float al2 = pt2 + __shfl_xor(pt2, 1);
        float al3 = pt3 + __shfl_xor(pt3, 1);
        float l0 = al0 + adv; l0 = fmaxf(l0, 0.2f * l0); float e0 = __expf(l0);
        float l1 = al1 + adv; l1 = fmaxf(l1, 0.2f * l1); float e1 = __expf(l1);
        float l2 = al2 + adv; l2 = fmaxf(l2, 0.2f * l2); float e2 = __expf(l2);
        float l3 = al3 + adv; l3 = fmaxf(l3, 0.2f * l3); float e3 = __expf(l3);
        se += e0 + e1 + e2 + e3;
        ax += e0 * h00 + e1 * h10 + e2 * h20 + e3 * h30;
        ay += e0 * h01 + e1 * h11 + e2 * h21 + e3 * h31;
        az += e0 * h02 + e1 * h12 + e2 * h22 + e3 * h32;
        aw += e0 * h03 + e1 * h13 + e2 * h23 + e3 * h33;
    }
    for (; p < p1; p++) {
        int s = csr[p];
        ushort4 v = *(const ushort4*)&Hs[s * 32 + q * 4];
        float h0 = h2f(v.x), h1 = h2f(v.y), h2 = h2f(v.z), h3 = h2f(v.w);
        float pt = h0 * aq0 + h1 * aq1 + h2 * aq2 + h3 * aq3;
        float al = pt + __shfl_xor(pt, 1);
        float l = al + adv; l = fmaxf(l, 0.2f * l);
        float e = __expf(l);
        se += e;
        ax += e * h0; ay += e * h1; az += e * h2; aw += e * h3;
    }
    const float inv = 1.f / (se + 1e-16f);
    float4 r;
    r.x = fmaxf(ax * inv, 0.f);
    r.y = fmaxf(ay * inv, 0.f);
    r.z = fmaxf(az * inv, 0.f);
    r.w = fmaxf(aw * inv, 0.f);
    *(float4*)&O[n * 32 + q * 4] = r;
}

// ---------- semantic reduce: one relation per block (fp32 weights) ----------
__global__ __launch_bounds__(256) void k_sem_reduce2(
        const float* __restrict__ O1, const float* __restrict__ O2,
        const float* __restrict__ kWl, const float* __restrict__ kbl,
        float* __restrict__ accum) {
    __shared__ float w[1056];
    __shared__ float sacc[32];
    const int r = (blockIdx.x >= NB_SEM) ? 1 : 0;
    const float* O = r ? O2 : O1;
    for (int i = threadIdx.x; i < 1024; i += 256) w[i] = kWl[i];
    if (threadIdx.x < 32) {
        w[1024 + threadIdx.x] = kbl[threadIdx.x];
        sacc[threadIdx.x] = 0.f;
    }
    __syncthreads();
    long n = (long)(blockIdx.x - r * NB_SEM) * 256 + threadIdx.x;
    float y[32];
    if (n < NA) {
        float x[32];
#pragma unroll
        for (int k = 0; k < 32; k++) x[k] = O[n * 32 + k];
#pragma unroll
        for (int f = 0; f < 32; f++) {
            float acc = w[1024 + f];
#pragma unroll
            for (int k = 0; k < 32; k++) acc += x[k] * w[k * 32 + f];
            y[f] = ftanh(acc);
        }
    } else {
#pragma unroll
        for (int f = 0; f < 32; f++) y[f] = 0.f;
    }
#pragma unroll
    for (int f = 0; f < 32; f++) {
        float v = y[f];
        for (int o = 32; o > 0; o >>= 1) v += __shfl_xor(v, o, 64);
        if ((threadIdx.x & 63) == 0) atomicAdd(&sacc[f], v);
    }
    __syncthreads();
    if (threadIdx.x < 32) atomicAdd(&accum[r * 32 + threadIdx.x], sacc[threadIdx.x]);
}

__global__ void k_sem_attn(const float* __restrict__ accum, float Ninv,
                           const float* __restrict__ q, float* __restrict__ attn) {
    if (threadIdx.x == 0) {
        float s0 = 0.f, s1 = 0.f;
        for (int f = 0; f < 32; f++) {
            float qf = q[f];
            s0 += accum[f] * Ninv * qf;
            s1 += accum[32 + f] * Ninv * qf;
        }
        float m = fmaxf(s0, s1);
        float e0 = __expf(s0 - m), e1 = __expf(s1 - m);
        float inv = 1.f / (e0 + e1);
        attn[0] = e0 * inv;
        attn[1] = e1 * inv;
    }
}

// ---------- fused combine + final linear (layer 3 only) ----------
__global__ void k_combine_final(const float* __restrict__ o1, const float* __restrict__ o2,
                                const float* __restrict__ attn,
                                const float* __restrict__ linW, const float* __restrict__ linb,
                                void* __restrict__ out, int N, const int* __restrict__ flagp) {
    int n = blockIdx.x * blockDim.x + threadIdx.x;
    if (n >= N) return;
    int f32 = *flagp;
    float w0 = attn[0], w1 = attn[1];
    float s0 = linb[0], s1 = linb[1];
    const float* p1 = &o1[(long)n * 32];
    const float* p2 = &o2[(long)n * 32];
#pragma unroll
    for (int f = 0; f < 32; f++) {
        float v = w0 * p1[f] + w1 * p2[f];
        v = (v > 0.f) ? v : 0.f;
        s0 += v * linW[f * 2];
        s1 += v * linW[f * 2 + 1];
    }
    if (f32) { ((float*)out)[n * 2] = s0; ((float*)out)[n * 2 + 1] = s1; }
    else {
        ((__hip_bfloat16*)out)[n * 2] = __float2bfloat16(s0);
        ((__hip_bfloat16*)out)[n * 2 + 1] = __float2bfloat16(s1);
    }
}

static inline int gblocks(long n) { return (int)((n + 255) / 256); }

extern "C" void kernel_launch(void* const* d_in, const int* in_sizes, int n_in,
                              void* d_out, int out_size, void* d_ws, size_t ws_size,
                              hipStream_t stream) {
    const void* x_addr = d_in[0];
    const void* x_tx   = d_in[1];
    const int* eat_s = (const int*)d_in[2];
    const int* eat_d = (const int*)d_in[3];
    const int* eta_s = (const int*)d_in[4];
    const int* eta_d = (const int*)d_in[5];
    const int* eaa_s = (const int*)d_in[6];
    const int* eaa_d = (const int*)d_in[7];
    const void* pW1  = d_in[8];
    const void* pb1  = d_in[9];
    const void* pW23 = d_in[10];
    const void* pb23 = d_in[11];
    const void* attS = d_in[12];
    const void* attD = d_in[13];
    const void* kW   = d_in[14];
    const void* kb   = d_in[15];
    const void* qv   = d_in[16];
    const void* linW = d_in[17];
    const void* linb = d_in[18];

    const size_t NA32 = (size_t)NA * 32, NT32 = (size_t)NT * 32;
    const size_t NA4 = (size_t)NA * 4, NT4 = (size_t)NT * 4;

    float* ws    = (float*)d_ws;
    float* h_aF  = ws;                   // fp16 rows (uses half the slot)
    float* h_tF  = h_aF + NA32;
    float* o_a1  = h_tF + NT32;
    float* o_a2  = o_a1 + NA32;
    float* o_tx  = o_a2 + NA32;
    float* ad1   = o_tx + NT32;          // TA dst alphas (addr)
    float* ad2   = ad1 + NA4;            // AA dst alphas (addr)
    float* ad0   = ad2 + NA4;            // AT dst alphas (tx)
    float* sem   = ad0 + NT4;            // 64 accum + 2 attn
    int*   flagp = (int*)(sem + 66);
    int*   off_at = flagp + 16;          // NT+1
    int*   off_ta = off_at + (NT + 1);   // NA+1
    int*   off_aa = off_ta + (NA + 1);   // NA+1
    int*   csr_at = off_aa + (NA + 1);   // E_AT
    int*   csr_ta = csr_at + E_AT;       // E_TA
    int*   csr_aa = csr_ta + E_TA;       // E_AA
    int*   gcnt   = csr_aa + E_AA;       // 1024
    int*   bbase  = gcnt + 1024;         // 1024
    int*   slot_at = bbase + 1024;       // P_AT*CAP
    int*   slot_ta = slot_at + P_AT * CAP;
    int*   slot_aa = slot_ta + P_TA * CAP;
    float* wts    = (float*)(slot_aa + (size_t)P_AA * CAP);   // fp32 weight cache

    unsigned short* h_a = (unsigned short*)h_aF;
    unsigned short* h_t = (unsigned short*)h_tF;

    k_detect<<<1, 256, 0, stream>>>(x_addr, flagp);
    k_cvtw<<<1, 256, 0, stream>>>(pW1, pb1, pW23, pb23, attS, attD, kW, kb, qv,
                                  linW, linb, wts, flagp);

    // ---- binned CSR build ----
    (void)hipMemsetAsync(gcnt, 0, 1024 * sizeof(int), stream);
    k_bin<<<CB_AT + CB_TA + CB_AA, 256, 0, stream>>>(
        eat_s, eat_d, eta_s, eta_d, eaa_s, eaa_d, gcnt, slot_at, slot_ta, slot_aa);
    k_binscan<<<1, 512, 0, stream>>>(gcnt, bbase, off_at, off_ta, off_aa);
    k_binsort<<<NBINS, 256, 0, stream>>>(gcnt, bbase, slot_at, slot_ta, slot_aa,
                                         off_at, off_ta, off_aa, csr_at, csr_ta, csr_aa);

    for (int l = 0; l < 3; l++) {
        if (l == 0) {
            k_proj2<64, 0><<<GPA + GPT, 64, 0, stream>>>(
                x_addr, x_tx, nullptr, sem + 64,
                wts + WO_W1, 0, 2048, wts + WO_B1, 0, 32,
                h_a, h_t, wts + WO_AD, 0, ad0, ad1, ad2, flagp, sem);
        } else {
            int wi = (l - 1) * 2;
            k_proj2<32, 1><<<GPA + GPT, 64, 0, stream>>>(
                o_a1, o_tx, o_a2, sem + 64,
                wts + WO_W23, (wi + 0) * 1024, (wi + 1) * 1024,
                wts + WO_B23, (wi + 0) * 32, (wi + 1) * 32,
                h_a, h_t, wts + WO_AD, l * 96, ad0, ad1, ad2, flagp, sem);
        }
        k_gather3<<<GB_AT + GB_TA + GB_AA, 256, 0, stream>>>(
            off_at, csr_at, off_ta, csr_ta, off_aa, csr_aa,
            ad0, ad1, ad2, h_a, h_t, o_tx, o_a1, o_a2, wts + WO_AS, l * 96);
        k_sem_reduce2<<<2 * NB_SEM, 256, 0, stream>>>(
            o_a1, o_a2, wts + WO_KW + l * 1024, wts + WO_KB + l * 32, sem);
        k_sem_attn<<<1, 64, 0, stream>>>(sem, 1.0f / NA, wts + WO_Q + l * 32, sem + 64);
        if (l == 2) {
            k_combine_final<<<gblocks(NA), 256, 0, stream>>>(o_a1, o_a2, sem + 64,
                                                             wts + WO_LW, wts + WO_LB,
                                                             d_out, NA, flagp);
        }
    }
}

// Round 6
// 662.415 us; speedup vs baseline: 1.5656x; 1.0433x over previous
//
#include <hip/hip_runtime.h>
#include <hip/hip_bf16.h>
#include <hip/hip_fp16.h>

#define NA 150000
#define NT 200000
#define E_AT 1000000
#define E_TA 1000000
#define E_AA 500000

#define CHK 2048           // edges per k_bin block
#define CAP 8192           // slot capacity per bin (max bin count ~3.8K)
#define P_AT 391           // ceil(NT/512)
#define P_TA 293           // ceil(NA/512)
#define P_AA 293
#define NBINS (P_AT + P_TA + P_AA)   // 977
#define CB_AT 489          // ceil(E_AT/CHK)
#define CB_TA 489
#define CB_AA 245

// gather grid partition: 32 dsts per 256-thread block (8 lanes per dst)
#define GB_AT 6250         // ceil(NT/32)
#define GB_TA 4688         // ceil(NA/32)
#define GB_AA 4688

// proj grid partition: 32 nodes per 256-thread block (8 lanes per node)
#define GA32 4688          // ceil(NA/32)
#define GT32 6250          // NT/32
#define NB_SEM 586         // ceil(NA/256) blocks per relation for sem reduce

// fp32 weight cache offsets (in ws)
#define WO_W1   0          // 2*64*32 = 4096
#define WO_B1   4096       // 64
#define WO_W23  4160       // 4096
#define WO_B23  8256       // 128
#define WO_AS   8384       // 288
#define WO_AD   8672       // 288
#define WO_KW   8960       // 3072
#define WO_KB   12032      // 96
#define WO_Q    12128      // 96
#define WO_LW   12224      // 64
#define WO_LB   12288      // 2
#define WT_TOT  12290

// ---------- dtype-flexible load: flag==1 -> fp32, flag==0 -> bf16 ----------
__device__ __forceinline__ float ldf(const void* p, long i, int f32) {
    if (f32) return ((const float*)p)[i];
    unsigned int u = ((const unsigned short*)p)[i];
    union { unsigned int ui; float f; } v; v.ui = u << 16;
    return v.f;
}
__device__ __forceinline__ float bf2f(unsigned short u) {
    union { unsigned int ui; float f; } v; v.ui = ((unsigned int)u) << 16;
    return v.f;
}
__device__ __forceinline__ float h2f(unsigned short u) {
    return __half2float(__ushort_as_half(u));
}
__device__ __forceinline__ unsigned short f2h(float x) {
    return __half_as_ushort(__float2half(x));
}
__device__ __forceinline__ float ftanh(float x) {
    x = fminf(fmaxf(x, -9.f), 9.f);
    float e = __expf(2.f * x);
    return (e - 1.f) / (e + 1.f);
}

// ---------- init: dtype detect + fp32 weight cache + gcnt zero (one dispatch) ----------
__global__ void k_init(const void* __restrict__ x,
                       const void* __restrict__ pW1, const void* __restrict__ pb1,
                       const void* __restrict__ pW23, const void* __restrict__ pb23,
                       const void* __restrict__ attS, const void* __restrict__ attD,
                       const void* __restrict__ kW, const void* __restrict__ kb,
                       const void* __restrict__ qv, const void* __restrict__ linW,
                       const void* __restrict__ linb,
                       float* __restrict__ wts, int* __restrict__ flagp,
                       int* __restrict__ gcnt) {
    __shared__ int cnt;
    const int t = threadIdx.x;
    if (t == 0) cnt = 0;
    __syncthreads();
    const unsigned short* u = (const unsigned short*)x;
    int wild = 0;
    for (int i = t; i < 4096; i += 256) {
        unsigned short v = u[i];
        int e = (v >> 7) & 0xFF;
        if (e > 133 || (e != 0 && e < 100)) wild++;
        else if (e == 0 && (v & 0x7F)) wild++;
    }
    atomicAdd(&cnt, wild);
    __syncthreads();
    const int f32 = (cnt > 1024) ? 1 : 0;
    if (t == 0) *flagp = f32;
    for (int i = t; i < 1024; i += 256) gcnt[i] = 0;
    for (int i = t; i < 4096; i += 256) wts[WO_W1 + i]  = ldf(pW1, i, f32);
    for (int i = t; i < 64;   i += 256) wts[WO_B1 + i]  = ldf(pb1, i, f32);
    for (int i = t; i < 4096; i += 256) wts[WO_W23 + i] = ldf(pW23, i, f32);
    for (int i = t; i < 128;  i += 256) wts[WO_B23 + i] = ldf(pb23, i, f32);
    for (int i = t; i < 288;  i += 256) wts[WO_AS + i]  = ldf(attS, i, f32);
    for (int i = t; i < 288;  i += 256) wts[WO_AD + i]  = ldf(attD, i, f32);
    for (int i = t; i < 3072; i += 256) wts[WO_KW + i]  = ldf(kW, i, f32);
    for (int i = t; i < 96;   i += 256) wts[WO_KB + i]  = ldf(kb, i, f32);
    for (int i = t; i < 96;   i += 256) wts[WO_Q + i]   = ldf(qv, i, f32);
    for (int i = t; i < 64;   i += 256) wts[WO_LW + i]  = ldf(linW, i, f32);
    for (int i = t; i < 2;    i += 256) wts[WO_LB + i]  = ldf(linb, i, f32);
}

// ========== projection: 8 lanes per node, X+W in LDS, high occupancy ==========
// 256-thread block = 32 nodes. Lane q in [0,8) owns output quad q*4..q*4+3.
// Per k4-step: 1 X float4 (broadcast within group; groups hit distinct banks
// via XS=K+4) + 4 W float4 (8 distinct addrs/wave = 32 banks once, rest
// broadcast) + 16 FMAs. LDS = (32*(K+4) + K*32)*4 B -> 16.7 KB @K=64 ->
// ~9 blocks/CU (36 waves). Epilogue thread-group-local: uint2 fp16 H store
// (64 B/node), attD dots closed by one shfl_xor(·,1).
// blocks [0,GA32)=addr, [GA32,GA32+GT32)=tx. LMODE 0: layer-1 (dtype-flagged);
// LMODE 1: addr=combine(o1,o2,attn)+relu, tx=fp32 o_tx.
// Block 0 zeroes the 64-float semantic accumulator.
template<int K, int LMODE>
__global__ __launch_bounds__(256) void k_proj2(
        const void* __restrict__ Xa, const void* __restrict__ Xt,
        const void* __restrict__ X2, const float* __restrict__ attn,
        const float* __restrict__ W, int wOffA, int wOffT,
        const float* __restrict__ Bv, int bOffA, int bOffT,
        unsigned short* __restrict__ Ha, unsigned short* __restrict__ Ht,
        const float* __restrict__ attD, int lBase,
        float* __restrict__ ad0, float* __restrict__ ad1, float* __restrict__ ad2,
        const int* __restrict__ flagp, float* __restrict__ zsem) {
    constexpr int XS = K + 4;
    constexpr int CPR = K / 4;           // float4 chunks per row
    constexpr int TOT4 = 32 * CPR;       // float4 chunks per tile
    __shared__ float Xs[32 * XS];
    __shared__ float Wl[K * 32];
    const int t = threadIdx.x;
    if (blockIdx.x == 0 && t < 64) zsem[t] = 0.f;
    const bool isA = blockIdx.x < GA32;
    const int bb = isA ? (int)blockIdx.x : (int)blockIdx.x - GA32;
    const int N = isA ? NA : NT;
    const int wOff = isA ? wOffA : wOffT;
    const int bOff = isA ? bOffA : bOffT;
    const long n0 = (long)bb * 32;
    for (int i = t; i < K * 32; i += 256) Wl[i] = W[wOff + i];
    if (LMODE == 1) {
        if (isA) {
            const float w0 = attn[0], w1 = attn[1];
            const float* A1 = (const float*)Xa;
            const float* A2 = (const float*)X2;
            for (int i = t; i < TOT4; i += 256) {
                int r = i / CPR, c = (i - r * CPR) * 4;
                long gr = n0 + r; if (gr >= N) gr = N - 1;
                float4 va = *(const float4*)&A1[gr * K + c];
                float4 vb = *(const float4*)&A2[gr * K + c];
                float4 o;
                o.x = fmaxf(w0 * va.x + w1 * vb.x, 0.f);
                o.y = fmaxf(w0 * va.y + w1 * vb.y, 0.f);
                o.z = fmaxf(w0 * va.z + w1 * vb.z, 0.f);
                o.w = fmaxf(w0 * va.w + w1 * vb.w, 0.f);
                *(float4*)&Xs[r * XS + c] = o;
            }
        } else {
            const float* Xf = (const float*)Xt;
            for (int i = t; i < TOT4; i += 256) {
                int r = i / CPR, c = (i - r * CPR) * 4;
                long gr = n0 + r; if (gr >= N) gr = N - 1;
                *(float4*)&Xs[r * XS + c] = *(const float4*)&Xf[gr * K + c];
            }
        }
    } else {
        const void* X = isA ? Xa : Xt;
        const int f32 = *flagp;
        if (f32) {
            const float* Xf = (const float*)X;
            for (int i = t; i < TOT4; i += 256) {
                int r = i / CPR, c = (i - r * CPR) * 4;
                long gr = n0 + r; if (gr >= N) gr = N - 1;
                *(float4*)&Xs[r * XS + c] = *(const float4*)&Xf[gr * K + c];
            }
        } else {
            const unsigned short* Xh = (const unsigned short*)X;
            for (int i = t; i < TOT4; i += 256) {
                int r = i / CPR, c = (i - r * CPR) * 4;
                long gr = n0 + r; if (gr >= N) gr = N - 1;
                ushort4 v = *(const ushort4*)&Xh[gr * K + c];
                float4 o;
                o.x = bf2f(v.x); o.y = bf2f(v.y); o.z = bf2f(v.z); o.w = bf2f(v.w);
                *(float4*)&Xs[r * XS + c] = o;
            }
        }
    }
    __syncthreads();
    const int g = t >> 3;        // node in tile
    const int q = t & 7;         // output quad
    const long n = n0 + g;
    float a0 = Bv[bOff + q * 4 + 0];
    float a1 = Bv[bOff + q * 4 + 1];
    float a2 = Bv[bOff + q * 4 + 2];
    float a3 = Bv[bOff + q * 4 + 3];
#pragma unroll 4
    for (int k4 = 0; k4 < K; k4 += 4) {
        float4 xv = *(const float4*)&Xs[g * XS + k4];
        float4 w0 = *(const float4*)&Wl[(k4 + 0) * 32 + q * 4];
        float4 w1 = *(const float4*)&Wl[(k4 + 1) * 32 + q * 4];
        float4 w2 = *(const float4*)&Wl[(k4 + 2) * 32 + q * 4];
        float4 w3 = *(const float4*)&Wl[(k4 + 3) * 32 + q * 4];
        a0 = fmaf(xv.x, w0.x, a0); a1 = fmaf(xv.x, w0.y, a1);
        a2 = fmaf(xv.x, w0.z, a2); a3 = fmaf(xv.x, w0.w, a3);
        a0 = fmaf(xv.y, w1.x, a0); a1 = fmaf(xv.y, w1.y, a1);
        a2 = fmaf(xv.y, w1.z, a2); a3 = fmaf(xv.y, w1.w, a3);
        a0 = fmaf(xv.z, w2.x, a0); a1 = fmaf(xv.z, w2.y, a1);
        a2 = fmaf(xv.z, w2.z, a2); a3 = fmaf(xv.z, w2.w, a3);
        a0 = fmaf(xv.w, w3.x, a0); a1 = fmaf(xv.w, w3.y, a1);
        a2 = fmaf(xv.w, w3.z, a2); a3 = fmaf(xv.w, w3.w, a3);
    }
    if (n < N) {
        unsigned short* Hh = isA ? Ha : Ht;
        unsigned int p01 = (unsigned)f2h(a0) | ((unsigned)f2h(a1) << 16);
        unsigned int p23 = (unsigned)f2h(a2) | ((unsigned)f2h(a3) << 16);
        *(uint2*)&Hh[n * 32 + q * 4] = make_uint2(p01, p23);
        const int hh = q >> 1;
        const int ai = lBase + q * 4;
        if (isA) {
            float p1 = a0 * attD[ai + 32] + a1 * attD[ai + 33]
                     + a2 * attD[ai + 34] + a3 * attD[ai + 35];
            float p2 = a0 * attD[ai + 64] + a1 * attD[ai + 65]
                     + a2 * attD[ai + 66] + a3 * attD[ai + 67];
            float s1 = p1 + __shfl_xor(p1, 1);
            float s2 = p2 + __shfl_xor(p2, 1);
            if (!(q & 1)) { ad1[n * 4 + hh] = s1; ad2[n * 4 + hh] = s2; }
        } else {
            float p0 = a0 * attD[ai] + a1 * attD[ai + 1]
                     + a2 * attD[ai + 2] + a3 * attD[ai + 3];
            float s0 = p0 + __shfl_xor(p0, 1);
            if (!(q & 1)) ad0[n * 4 + hh] = s0;
        }
    }
}

// ================= binned CSR build =================
// Phase A: bin edges by dst>>9 into fixed-capacity slots. pack = (ldst<<18)|src.
__global__ __launch_bounds__(256) void k_bin(
        const int* __restrict__ eat_s, const int* __restrict__ eat_d,
        const int* __restrict__ eta_s, const int* __restrict__ eta_d,
        const int* __restrict__ eaa_s, const int* __restrict__ eaa_d,
        int* __restrict__ gcnt,
        int* __restrict__ slot_at, int* __restrict__ slot_ta, int* __restrict__ slot_aa) {
    __shared__ int hist[P_AT];   // max bins per relation
    int b = blockIdx.x, t = threadIdx.x;
    const int *src, *dst; int E, P, seg; int* slot;
    if (b < CB_AT)              { src = eat_s; dst = eat_d; E = E_AT; P = P_AT; seg = 0;            slot = slot_at; }
    else if (b < CB_AT + CB_TA) { b -= CB_AT;  src = eta_s; dst = eta_d; E = E_TA; P = P_TA; seg = P_AT;        slot = slot_ta; }
    else                        { b -= CB_AT + CB_TA; src = eaa_s; dst = eaa_d; E = E_AA; P = P_AA; seg = P_AT + P_TA; slot = slot_aa; }
    long e0 = (long)b * CHK;
    for (int i = t; i < P; i += 256) hist[i] = 0;
    __syncthreads();
    for (int k = 0; k < CHK; k += 256) {
        long e = e0 + k + t;
        if (e < E) atomicAdd(&hist[dst[e] >> 9], 1);
    }
    __syncthreads();
    // reserve runs: hist[i] becomes this block's base cursor within bin i
    for (int i = t; i < P; i += 256) {
        int v = hist[i];
        hist[i] = atomicAdd(&gcnt[seg + i], v);
    }
    __syncthreads();
    for (int k = 0; k < CHK; k += 256) {
        long e = e0 + k + t;
        if (e < E) {
            int d = dst[e];
            int bin = d >> 9;
            int pos = atomicAdd(&hist[bin], 1);
            slot[bin * CAP + pos] = ((d & 511) << 18) | src[e];
        }
    }
}

// Phase A2: exclusive-scan bin counts per relation -> bin bases; write off[N].
__global__ void k_binscan(const int* __restrict__ gcnt, int* __restrict__ bbase,
                          int* __restrict__ off_at, int* __restrict__ off_ta,
                          int* __restrict__ off_aa) {
    __shared__ int sa[512], sb[512];
    int t = threadIdx.x;  // 512 threads
    const int segs[4] = {0, P_AT, P_AT + P_TA, NBINS};
    for (int r = 0; r < 3; r++) {
        int s0 = segs[r], P = segs[r + 1] - s0;
        sa[t] = (t < P) ? gcnt[s0 + t] : 0;
        __syncthreads();
        int* in = sa; int* out = sb;
        for (int o = 1; o < 512; o <<= 1) {
            out[t] = in[t] + (t >= o ? in[t - o] : 0);
            __syncthreads();
            int* tmp = in; in = out; out = tmp;
        }
        if (t < P) bbase[s0 + t] = (t ? in[t - 1] : 0);
        __syncthreads();
    }
    if (t == 0) { off_at[NT] = E_AT; off_ta[NA] = E_TA; off_aa[NA] = E_AA; }
}

// Phase B: per-bin LDS counting sort -> exact CSR + off.
__global__ __launch_bounds__(256) void k_binsort(
        const int* __restrict__ gcnt, const int* __restrict__ bbase,
        const int* __restrict__ slot_at, const int* __restrict__ slot_ta,
        const int* __restrict__ slot_aa,
        int* __restrict__ off_at, int* __restrict__ off_ta, int* __restrict__ off_aa,
        int* __restrict__ csr_at, int* __restrict__ csr_ta, int* __restrict__ csr_aa) {
    __shared__ int sa[512], sb[512], cur[512];
    int b = blockIdx.x, t = threadIdx.x;
    const int* slot; int* off; int* csr; int N, bin, seg;
    if (b < P_AT)              { slot = slot_at; off = off_at; csr = csr_at; N = NT; bin = b;                seg = 0; }
    else if (b < P_AT + P_TA)  { slot = slot_ta; off = off_ta; csr = csr_ta; N = NA; bin = b - P_AT;         seg = P_AT; }
    else                       { slot = slot_aa; off = off_aa; csr = csr_aa; N = NA; bin = b - P_AT - P_TA;  seg = P_AT + P_TA; }
    const int cnt  = gcnt[seg + bin];
    const int base = bbase[seg + bin];
    const int* sp = &slot[bin * CAP];
    sa[t] = 0; sa[t + 256] = 0;
    __syncthreads();
    for (int i = t; i < cnt; i += 256) atomicAdd(&sa[sp[i] >> 18], 1);
    __syncthreads();
    int* in = sa; int* out = sb;
    for (int o = 1; o < 512; o <<= 1) {
        for (int i = t; i < 512; i += 256)
            out[i] = in[i] + (i >= o ? in[i - o] : 0);
        __syncthreads();
        int* tmp = in; in = out; out = tmp;
    }
    for (int i = t; i < 512; i += 256) {
        int excl = i ? in[i - 1] : 0;
        cur[i] = excl;
        int gd = bin * 512 + i;
        if (gd < N) off[gd] = base + excl;
    }
    __syncthreads();
    for (int i = t; i < cnt; i += 256) {
        int pk = sp[i];
        int pos = atomicAdd(&cur[pk >> 18], 1);
        csr[base + pos] = pk & 0x3FFFF;
    }
}

// ========== tri-relation gather: 8 lanes/dst, fp16 H, in-kernel src alpha ==========
__global__ __launch_bounds__(256) void k_gather3(
        const int* __restrict__ off_at, const int* __restrict__ csr_at,
        const int* __restrict__ off_ta, const int* __restrict__ csr_ta,
        const int* __restrict__ off_aa, const int* __restrict__ csr_aa,
        const float* __restrict__ ad0, const float* __restrict__ ad1,
        const float* __restrict__ ad2,
        const unsigned short* __restrict__ h_a, const unsigned short* __restrict__ h_t,
        float* __restrict__ o_tx, float* __restrict__ o_a1, float* __restrict__ o_a2,
        const float* __restrict__ attS, int lBase) {
    int b = blockIdx.x;
    const int *off, *csr;
    const float *ad_;
    const unsigned short* Hs;
    float* O;
    int N, attOff;
    if (b < GB_AT) {
        off = off_at; csr = csr_at; ad_ = ad0; Hs = h_a; O = o_tx; N = NT;
        attOff = lBase;            // edge type 0 (A->T)
    } else if (b < GB_AT + GB_TA) {
        b -= GB_AT;
        off = off_ta; csr = csr_ta; ad_ = ad1; Hs = h_t; O = o_a1; N = NA;
        attOff = lBase + 32;       // edge type 1 (T->A)
    } else {
        b -= GB_AT + GB_TA;
        off = off_aa; csr = csr_aa; ad_ = ad2; Hs = h_a; O = o_a2; N = NA;
        attOff = lBase + 64;       // edge type 2 (A->A)
    }
    const int t = threadIdx.x;
    const int q = t & 7;          // column quad 0..7
    const int hh = q >> 1;        // head
    const int n = b * 32 + (t >> 3);
    if (n >= N) return;
    const float4 aq = *(const float4*)&attS[attOff + q * 4];
    const float aq0 = aq.x, aq1 = aq.y, aq2 = aq.z, aq3 = aq.w;
    const float adv = ad_[n * 4 + hh];
    const int p0 = off[n], p1 = off[n + 1];
    float ax = 0.f, ay = 0.f, az = 0.f, aw = 0.f, se = 0.f;
    int p = p0;
    for (; p + 4 <= p1; p += 4) {
        int s0 = csr[p], s1 = csr[p + 1], s2 = csr[p + 2], s3 = csr[p + 3];
        ushort4 v0 = *(const ushort4*)&Hs[s0 * 32 + q * 4];
        ushort4 v1 = *(const ushort4*)&Hs[s1 * 32 + q * 4];
        ushort4 v2 = *(const ushort4*)&Hs[s2 * 32 + q * 4];
        ushort4 v3 = *(const ushort4*)&Hs[s3 * 32 + q * 4];
        float h00 = h2f(v0.x), h01 = h2f(v0.y), h02 = h2f(v0.z), h03 = h2f(v0.w);
        float h10 = h2f(v1.x), h11 = h2f(v1.y), h12 = h2f(v1.z), h13 = h2f(v1.w);
        float h20 = h2f(v2.x), h21 = h2f(v2.y), h22 = h2f(v2.z), h23 = h2f(v2.w);
        float h30 = h2f(v3.x), h31 = h2f(v3.y), h32 = h2f(v3.z), h33 = h2f(v3.w);
        float pt0 = h00 * aq0 + h01 * aq1 + h02 * aq2 + h03 * aq3;
        float pt1 = h10 * aq0 + h11 * aq1 + h12 * aq2 + h13 * aq3;
        float pt2 = h20 * aq0 + h21 * aq1 + h22 * aq2 + h23 * aq3;
        float pt3 = h30 * aq0 + h31 * aq1 + h32 * aq2 + h33 * aq3;
        float al0 = pt0 + __shfl_xor(pt0, 1);
        float al1 = pt1 + __shfl_xor(pt1, 1);
        float al2 = pt2 + __shfl_xor(pt2, 1);
        float al3 = pt3 + __shfl_xor(pt3, 1);
        float l0 = al0 + adv; l0 = fmaxf(l0, 0.2f * l0); float e0 = __expf(l0);
        float l1 = al1 + adv; l1 = fmaxf(l1, 0.2f * l1); float e1 = __expf(l1);
        float l2 = al2 + adv; l2 = fmaxf(l2, 0.2f * l2); float e2 = __expf(l2);
        float l3 = al3 + adv; l3 = fmaxf(l3, 0.2f * l3); float e3 = __expf(l3);
        se += e0 + e1 + e2 + e3;
        ax += e0 * h00 + e1 * h10 + e2 * h20 + e3 * h30;
        ay += e0 * h01 + e1 * h11 + e2 * h21 + e3 * h31;
        az += e0 * h02 + e1 * h12 + e2 * h22 + e3 * h32;
        aw += e0 * h03 + e1 * h13 + e2 * h23 + e3 * h33;
    }
    for (; p < p1; p++) {
        int s = csr[p];
        ushort4 v = *(const ushort4*)&Hs[s * 32 + q * 4];
        float h0 = h2f(v.x), h1 = h2f(v.y), h2 = h2f(v.z), h3 = h2f(v.w);
        float pt = h0 * aq0 + h1 * aq1 + h2 * aq2 + h3 * aq3;
        float al = pt + __shfl_xor(pt, 1);
        float l = al + adv; l = fmaxf(l, 0.2f * l);
        float e = __expf(l);
        se += e;
        ax += e * h0; ay += e * h1; az += e * h2; aw += e * h3;
    }
    const float inv = 1.f / (se + 1e-16f);
    float4 r;
    r.x = fmaxf(ax * inv, 0.f);
    r.y = fmaxf(ay * inv, 0.f);
    r.z = fmaxf(az * inv, 0.f);
    r.w = fmaxf(aw * inv, 0.f);
    *(float4*)&O[n * 32 + q * 4] = r;
}

// ---------- semantic reduce: one relation per block (fp32 weights) ----------
__global__ __launch_bounds__(256) void k_sem_reduce2(
        const float* __restrict__ O1, const float* __restrict__ O2,
        const float* __restrict__ kWl, const float* __restrict__ kbl,
        float* __restrict__ accum) {
    __shared__ float w[1056];
    __shared__ float sacc[32];
    const int r = (blockIdx.x >= NB_SEM) ? 1 : 0;
    const float* O = r ? O2 : O1;
    for (int i = threadIdx.x; i < 1024; i += 256) w[i] = kWl[i];
    if (threadIdx.x < 32) {
        w[1024 + threadIdx.x] = kbl[threadIdx.x];
        sacc[threadIdx.x] = 0.f;
    }
    __syncthreads();
    long n = (long)(blockIdx.x - r * NB_SEM) * 256 + threadIdx.x;
    float y[32];
    if (n < NA) {
        float x[32];
#pragma unroll
        for (int k = 0; k < 32; k++) x[k] = O[n * 32 + k];
#pragma unroll
        for (int f = 0; f < 32; f++) {
            float acc = w[1024 + f];
#pragma unroll
            for (int k = 0; k < 32; k++) acc += x[k] * w[k * 32 + f];
            y[f] = ftanh(acc);
        }
    } else {
#pragma unroll
        for (int f = 0; f < 32; f++) y[f] = 0.f;
    }
#pragma unroll
    for (int f = 0; f < 32; f++) {
        float v = y[f];
        for (int o = 32; o > 0; o >>= 1) v += __shfl_xor(v, o, 64);
        if ((threadIdx.x & 63) == 0) atomicAdd(&sacc[f], v);
    }
    __syncthreads();
    if (threadIdx.x < 32) atomicAdd(&accum[r * 32 + threadIdx.x], sacc[threadIdx.x]);
}

__global__ void k_sem_attn(const float* __restrict__ accum, float Ninv,
                           const float* __restrict__ q, float* __restrict__ attn) {
    if (threadIdx.x == 0) {
        float s0 = 0.f, s1 = 0.f;
        for (int f = 0; f < 32; f++) {
            float qf = q[f];
            s0 += accum[f] * Ninv * qf;
            s1 += accum[32 + f] * Ninv * qf;
        }
        float m = fmaxf(s0, s1);
        float e0 = __expf(s0 - m), e1 = __expf(s1 - m);
        float inv = 1.f / (e0 + e1);
        attn[0] = e0 * inv;
        attn[1] = e1 * inv;
    }
}

// ---------- fused combine + final linear (layer 3 only) ----------
__global__ void k_combine_final(const float* __restrict__ o1, const float* __restrict__ o2,
                                const float* __restrict__ attn,
                                const float* __restrict__ linW, const float* __restrict__ linb,
                                void* __restrict__ out, int N, const int* __restrict__ flagp) {
    int n = blockIdx.x * blockDim.x + threadIdx.x;
    if (n >= N) return;
    int f32 = *flagp;
    float w0 = attn[0], w1 = attn[1];
    float s0 = linb[0], s1 = linb[1];
    const float* p1 = &o1[(long)n * 32];
    const float* p2 = &o2[(long)n * 32];
#pragma unroll
    for (int f = 0; f < 32; f++) {
        float v = w0 * p1[f] + w1 * p2[f];
        v = (v > 0.f) ? v : 0.f;
        s0 += v * linW[f * 2];
        s1 += v * linW[f * 2 + 1];
    }
    if (f32) { ((float*)out)[n * 2] = s0; ((float*)out)[n * 2 + 1] = s1; }
    else {
        ((__hip_bfloat16*)out)[n * 2] = __float2bfloat16(s0);
        ((__hip_bfloat16*)out)[n * 2 + 1] = __float2bfloat16(s1);
    }
}

static inline int gblocks(long n) { return (int)((n + 255) / 256); }

extern "C" void kernel_launch(void* const* d_in, const int* in_sizes, int n_in,
                              void* d_out, int out_size, void* d_ws, size_t ws_size,
                              hipStream_t stream) {
    const void* x_addr = d_in[0];
    const void* x_tx   = d_in[1];
    const int* eat_s = (const int*)d_in[2];
    const int* eat_d = (const int*)d_in[3];
    const int* eta_s = (const int*)d_in[4];
    const int* eta_d = (const int*)d_in[5];
    const int* eaa_s = (const int*)d_in[6];
    const int* eaa_d = (const int*)d_in[7];
    const void* pW1  = d_in[8];
    const void* pb1  = d_in[9];
    const void* pW23 = d_in[10];
    const void* pb23 = d_in[11];
    const void* attS = d_in[12];
    const void* attD = d_in[13];
    const void* kW   = d_in[14];
    const void* kb   = d_in[15];
    const void* qv   = d_in[16];
    const void* linW = d_in[17];
    const void* linb = d_in[18];

    const size_t NA32 = (size_t)NA * 32, NT32 = (size_t)NT * 32;
    const size_t NA4 = (size_t)NA * 4, NT4 = (size_t)NT * 4;

    float* ws    = (float*)d_ws;
    float* h_aF  = ws;                   // fp16 rows (uses half the slot)
    float* h_tF  = h_aF + NA32;
    float* o_a1  = h_tF + NT32;
    float* o_a2  = o_a1 + NA32;
    float* o_tx  = o_a2 + NA32;
    float* ad1   = o_tx + NT32;          // TA dst alphas (addr)
    float* ad2   = ad1 + NA4;            // AA dst alphas (addr)
    float* ad0   = ad2 + NA4;            // AT dst alphas (tx)
    float* sem   = ad0 + NT4;            // 64 accum + 2 attn
    int*   flagp = (int*)(sem + 66);
    int*   off_at = flagp + 16;          // NT+1
    int*   off_ta = off_at + (NT + 1);   // NA+1
    int*   off_aa = off_ta + (NA + 1);   // NA+1
    int*   csr_at = off_aa + (NA + 1);   // E_AT
    int*   csr_ta = csr_at + E_AT;       // E_TA
    int*   csr_aa = csr_ta + E_TA;       // E_AA
    int*   gcnt   = csr_aa + E_AA;       // 1024
    int*   bbase  = gcnt + 1024;         // 1024
    int*   slot_at = bbase + 1024;       // P_AT*CAP
    int*   slot_ta = slot_at + P_AT * CAP;
    int*   slot_aa = slot_ta + P_TA * CAP;
    float* wts    = (float*)(slot_aa + (size_t)P_AA * CAP);   // fp32 weight cache

    unsigned short* h_a = (unsigned short*)h_aF;
    unsigned short* h_t = (unsigned short*)h_tF;

    k_init<<<1, 256, 0, stream>>>(x_addr, pW1, pb1, pW23, pb23, attS, attD,
                                  kW, kb, qv, linW, linb, wts, flagp, gcnt);

    // ---- binned CSR build ----
    k_bin<<<CB_AT + CB_TA + CB_AA, 256, 0, stream>>>(
        eat_s, eat_d, eta_s, eta_d, eaa_s, eaa_d, gcnt, slot_at, slot_ta, slot_aa);
    k_binscan<<<1, 512, 0, stream>>>(gcnt, bbase, off_at, off_ta, off_aa);
    k_binsort<<<NBINS, 256, 0, stream>>>(gcnt, bbase, slot_at, slot_ta, slot_aa,
                                         off_at, off_ta, off_aa, csr_at, csr_ta, csr_aa);

    for (int l = 0; l < 3; l++) {
        if (l == 0) {
            k_proj2<64, 0><<<GA32 + GT32, 256, 0, stream>>>(
                x_addr, x_tx, nullptr, sem + 64,
                wts + WO_W1, 0, 2048, wts + WO_B1, 0, 32,
                h_a, h_t, wts + WO_AD, 0, ad0, ad1, ad2, flagp, sem);
        } else {
            int wi = (l - 1) * 2;
            k_proj2<32, 1><<<GA32 + GT32, 256, 0, stream>>>(
                o_a1, o_tx, o_a2, sem + 64,
                wts + WO_W23, (wi + 0) * 1024, (wi + 1) * 1024,
                wts + WO_B23, (wi + 0) * 32, (wi + 1) * 32,
                h_a, h_t, wts + WO_AD, l * 96, ad0, ad1, ad2, flagp, sem);
        }
        k_gather3<<<GB_AT + GB_TA + GB_AA, 256, 0, stream>>>(
            off_at, csr_at, off_ta, csr_ta, off_aa, csr_aa,
            ad0, ad1, ad2, h_a, h_t, o_tx, o_a1, o_a2, wts + WO_AS, l * 96);
        k_sem_reduce2<<<2 * NB_SEM, 256, 0, stream>>>(
            o_a1, o_a2, wts + WO_KW + l * 1024, wts + WO_KB + l * 32, sem);
        k_sem_attn<<<1, 64, 0, stream>>>(sem, 1.0f / NA, wts + WO_Q + l * 32, sem + 64);
        if (l == 2) {
            k_combine_final<<<gblocks(NA), 256, 0, stream>>>(o_a1, o_a2, sem + 64,
                                                             wts + WO_LW, wts + WO_LB,
                                                             d_out, NA, flagp);
        }
    }
}